// Round 2
// baseline (4615.994 us; speedup 1.0000x reference)
//
#include <hip/hip_runtime.h>
#include <math.h>

#define BN_EPS 1e-5f
#define HCONST 0.1f
#define RED_BLOCKS 1024

// ============================ utility ============================
__global__ void k_zeroi(int* __restrict__ p, int n){
  int i = blockIdx.x*blockDim.x + threadIdx.x;
  if (i < n) p[i] = 0;
}

// ============================ setup kernels ============================
__global__ void k_deg(const int* __restrict__ ei, int* __restrict__ cnt, int E){
  int e = blockIdx.x*blockDim.x + threadIdx.x;
  if (e < E) atomicAdd(&cnt[ei[e]], 1);
}

__global__ void k_dinv(const int* __restrict__ cnt, float* __restrict__ dinv, int n){
  int i = blockIdx.x*blockDim.x + threadIdx.x;
  if (i < n) dinv[i] = 1.0f/sqrtf((float)(cnt[i]+1));   // deg includes self-loop
}

__global__ __launch_bounds__(1024) void k_scan(const int* __restrict__ cnt, int* __restrict__ rowptr, int n){
  __shared__ int buf[1024];
  __shared__ int carry;
  int t = threadIdx.x;
  if (t==0) carry = 0;
  __syncthreads();
  for (int base=0; base<n; base+=1024){
    int v = (base+t<n) ? cnt[base+t] : 0;
    buf[t]=v; __syncthreads();
    for (int off=1; off<1024; off<<=1){
      int x = (t>=off) ? buf[t-off] : 0;
      __syncthreads();
      buf[t] += x;
      __syncthreads();
    }
    if (base+t<n) rowptr[base+t] = carry + buf[t] - v;   // exclusive
    __syncthreads();
    if (t==1023) carry += buf[1023];
    __syncthreads();
  }
  if (t==0) rowptr[n] = carry;
}

__global__ void k_fill(const int* __restrict__ ei, int E, const int* __restrict__ rowptr,
                       int* __restrict__ cnt, int* __restrict__ colidx){
  int e = blockIdx.x*blockDim.x + threadIdx.x;
  if (e < E){
    int s = ei[e];
    int pos = atomicAdd(&cnt[s],1);
    colidx[rowptr[s]+pos] = ei[E+e];
  }
}

// M = Wq^T Wk ; u = Wk^T bq ; v = Wq^T bk ; d0 = bq.bk
__global__ __launch_bounds__(256) void k_mprep(const float* __restrict__ Wq, const float* __restrict__ bq,
                                               const float* __restrict__ Wk, const float* __restrict__ bk,
                                               float* __restrict__ M, float* __restrict__ uvd){
  __shared__ float wqc[2][128];
  int t = threadIdx.x;
  int r = t>>7, e = t&127;
  int c0 = blockIdx.x*2;
  wqc[r][e] = Wq[(size_t)e*128 + (c0+r)];   // Wq[i][c], i=e
  __syncthreads();
  float acc = 0.f;
  for (int i=0;i<128;i++) acc += wqc[r][i]*Wk[(size_t)i*128 + e];
  M[(size_t)(c0+r)*128 + e] = acc;
  if (blockIdx.x==0){
    if (t<128){
      float au=0.f, av=0.f;
      for (int i=0;i<128;i++){ au += bq[i]*Wk[(size_t)i*128+t]; av += Wq[(size_t)i*128+t]*bk[i]; }
      uvd[t] = au; uvd[128+t] = av;
    }
    if (t==0){
      float d=0.f; for (int i=0;i<128;i++) d += bq[i]*bk[i];
      uvd[256] = d;
    }
  }
}

// emb: acts[l][n][c] = relu(bn(chw[c]*T[n,l]+chb[c])) for l=0..3, and l=11 -> TS
__global__ void k_emb(const float* __restrict__ T, const float* __restrict__ chw, const float* __restrict__ chb,
                      const float* __restrict__ bos, float* __restrict__ A0, float* __restrict__ A1,
                      float* __restrict__ A2, float* __restrict__ A3, float* __restrict__ TS, int n){
  int i = blockIdx.x*blockDim.x + threadIdx.x;
  if (i >= n*128) return;
  int node = i>>7, c = i&127;
  float w = chw[c], cb2 = chb[c];
  float g = bos[c], b2 = bos[128+c], m = bos[256+c], v = bos[384+c];
  float rs = rsqrtf(v+BN_EPS)*g;
  const float* Tr = T + (size_t)node*12;
  float x;
  x = w*Tr[0]+cb2;  A0[i] = fmaxf((x-m)*rs+b2, 0.f);
  x = w*Tr[1]+cb2;  A1[i] = fmaxf((x-m)*rs+b2, 0.f);
  x = w*Tr[2]+cb2;  A2[i] = fmaxf((x-m)*rs+b2, 0.f);
  x = w*Tr[3]+cb2;  A3[i] = fmaxf((x-m)*rs+b2, 0.f);
  x = w*Tr[11]+cb2; TS[i] = fmaxf((x-m)*rs+b2, 0.f);
}

// te[n,l] = silu(sum_c te_w[c]*tf[n,c,l] + te_b)
__global__ void k_te(const float* __restrict__ tf, const float* __restrict__ tew, const float* __restrict__ teb,
                     float* __restrict__ te, int n){
  int idx = blockIdx.x*blockDim.x + threadIdx.x;
  if (idx >= n*12) return;
  int node = idx/12, l = idx%12;
  float acc = teb[0];
  const float* p = tf + (size_t)node*240 + l;
  #pragma unroll
  for (int c=0;c<20;c++) acc += tew[c]*p[c*12];
  te[idx] = acc/(1.0f+expf(-acc));
}

// ============================ generic GEMM ============================
// out[n, 0..127] = EPI( sum over concat parts A_p @ W_p^T + biases )
// EPI: 0 = bn+relu, 1 = none, 2 = clip(-1,1), 3 = QK-score epilogue (no out write)
template<int EPI>
__global__ __launch_bounds__(256) void gemm_kernel(
  const float* __restrict__ A0p, int w0, const float* __restrict__ W0p, int ws0, const float* __restrict__ b0p,
  const float* __restrict__ A1p, int w1, const float* __restrict__ W1p, int ws1, const float* __restrict__ b1p,
  const float* __restrict__ A2p, int w2, const float* __restrict__ W2p, int ws2, const float* __restrict__ b2p,
  const float* __restrict__ bnp, float* __restrict__ outp, int nrows,
  const float* __restrict__ e0, const float* __restrict__ e1,
  const float* __restrict__ e2, const float* __restrict__ e3,
  const float* __restrict__ uvd, float* __restrict__ score, int kidx)
{
  __shared__ float As[32][68];    // k-major A tile (64 rows)
  __shared__ float Ws[32][132];   // k-major W tile (128 cols)
  const int t = threadIdx.x;
  const int K = w0 + w1 + w2;
  const int n0 = blockIdx.x*64;
  float acc[8][4];
  #pragma unroll
  for (int r=0;r<8;r++)
    #pragma unroll
    for (int c=0;c<4;c++) acc[r][c]=0.f;
  const int rb = (t>>5)*8, cb = (t&31)*4;

  for (int k0=0; k0<K; k0+=32){
    { // load A chunk (64 x 32)
      int row = t>>2, kg = (t&3)*8;
      int gr = n0+row;
      #pragma unroll
      for (int i=0;i<8;i++){
        int k = k0+kg+i; float v = 0.f;
        if (gr<nrows && k<K){
          if (k<w0)            v = A0p[(size_t)gr*w0 + k];
          else if (k<w0+w1)    v = A1p[(size_t)gr*w1 + (k-w0)];
          else                 v = A2p[(size_t)gr*w2 + (k-w0-w1)];
        }
        As[kg+i][row] = v;
      }
    }
    { // load W chunk (128 x 32) k-major
      int c = t>>1, kg = (t&1)*16;
      #pragma unroll
      for (int i=0;i<16;i++){
        int k = k0+kg+i; float v = 0.f;
        if (k<K){
          if (k<w0)            v = W0p[(size_t)c*ws0 + k];
          else if (k<w0+w1)    v = W1p[(size_t)c*ws1 + (k-w0)];
          else                 v = W2p[(size_t)c*ws2 + (k-w0-w1)];
        }
        Ws[kg+i][c] = v;
      }
    }
    __syncthreads();
    #pragma unroll
    for (int kk=0;kk<32;kk++){
      float4 w4  = *(const float4*)&Ws[kk][cb];
      float4 a4  = *(const float4*)&As[kk][rb];
      float4 a4b = *(const float4*)&As[kk][rb+4];
      float a[8] = {a4.x,a4.y,a4.z,a4.w,a4b.x,a4b.y,a4b.z,a4b.w};
      float w[4] = {w4.x,w4.y,w4.z,w4.w};
      #pragma unroll
      for (int r=0;r<8;r++)
        #pragma unroll
        for (int c=0;c<4;c++) acc[r][c] += a[r]*w[c];
    }
    __syncthreads();
  }

  if constexpr (EPI==3){
    // score epilogue: s[l][kidx] for each row = a_l.(G+v) + u.a_k + d0
    float4 u4 = *(const float4*)&uvd[cb];
    float4 v4 = *(const float4*)&uvd[128+cb];
    float d0 = uvd[256];
    #pragma unroll
    for (int r=0;r<8;r++){
      int gr = n0+rb+r;
      bool ok = gr < nrows;
      size_t bidx = ok ? ((size_t)gr*128 + cb) : 0;
      float gx = acc[r][0]+v4.x, gy = acc[r][1]+v4.y, gz = acc[r][2]+v4.z, gw = acc[r][3]+v4.w;
      float dd[5] = {0,0,0,0,0};
      const float* eptr[4] = {e0,e1,e2,e3};
      #pragma unroll
      for (int l=0;l<4;l++){
        float4 a4 = ok ? *(const float4*)&eptr[l][bidx] : make_float4(0,0,0,0);
        dd[l] = a4.x*gx + a4.y*gy + a4.z*gz + a4.w*gw;
        if (l==kidx) dd[4] = a4.x*u4.x + a4.y*u4.y + a4.z*u4.z + a4.w*u4.w;
      }
      #pragma unroll
      for (int off=1; off<32; off<<=1)
        #pragma unroll
        for (int i=0;i<5;i++) dd[i] += __shfl_xor(dd[i], off);
      if (ok && (t&31)==0){
        #pragma unroll
        for (int l=0;l<4;l++) score[(size_t)gr*16 + l*4 + kidx] = dd[l] + dd[4] + d0;
      }
    }
    return;
  } else {
    float bias[4] = {0,0,0,0};
    #pragma unroll
    for (int c=0;c<4;c++){
      if (b0p) bias[c] += b0p[cb+c];
      if (b1p) bias[c] += b1p[cb+c];
      if (b2p) bias[c] += b2p[cb+c];
    }
    float g[4],bb[4],mm[4],vv[4];
    if constexpr (EPI==0){
      #pragma unroll
      for (int c=0;c<4;c++){ g[c]=bnp[cb+c]; bb[c]=bnp[128+cb+c]; mm[c]=bnp[256+cb+c]; vv[c]=bnp[384+cb+c]; }
    }
    #pragma unroll
    for (int r=0;r<8;r++){
      int gr = n0+rb+r;
      if (gr < nrows){
        float4 o;
        float xv[4];
        #pragma unroll
        for (int c=0;c<4;c++){
          float x = acc[r][c] + bias[c];
          if constexpr (EPI==0) x = fmaxf((x-mm[c])*rsqrtf(vv[c]+BN_EPS)*g[c]+bb[c], 0.f);
          if constexpr (EPI==2) x = fminf(fmaxf(x,-1.f),1.f);
          xv[c]=x;
        }
        o.x=xv[0]; o.y=xv[1]; o.z=xv[2]; o.w=xv[3];
        *(float4*)&outp[(size_t)gr*128 + cb] = o;
      }
    }
  }
}

// ============================ attention softmax ============================
__global__ __launch_bounds__(256) void k_soft(const float* __restrict__ score, const float* __restrict__ mhaf,
                                              float* __restrict__ Cpart, int n){
  __shared__ float lds[4][16];
  const int t = threadIdx.x;
  const int nl = blockIdx.x*64 + (t>>2);
  const int l  = t&3;
  float val[4];
  if (nl < n){
    float4 s4 = *(const float4*)&score[(size_t)nl*16 + l*4];
    const float SCALE = 0.08838834764831845f;  // 1/sqrt(128)
    float s0=s4.x*SCALE, s1=s4.y*SCALE, s2=s4.z*SCALE, s3=s4.w*SCALE;
    float m = fmaxf(fmaxf(s0,s1),fmaxf(s2,s3));
    float p0=expf(s0-m),p1=expf(s1-m),p2=expf(s2-m),p3=expf(s3-m);
    float rf = fmaxf(mhaf[0],0.f);
    float inv = rf/(p0+p1+p2+p3);
    val[0]=logf(p0*inv+1e-4f); val[1]=logf(p1*inv+1e-4f);
    val[2]=logf(p2*inv+1e-4f); val[3]=logf(p3*inv+1e-4f);
  } else {
    val[0]=val[1]=val[2]=val[3]=0.f;
  }
  #pragma unroll
  for (int off=4; off<64; off<<=1)
    #pragma unroll
    for (int k2=0;k2<4;k2++) val[k2] += __shfl_xor(val[k2], off);
  const int wv = t>>6, lane = t&63;
  if (lane < 4){
    #pragma unroll
    for (int k2=0;k2<4;k2++) lds[wv][lane*4+k2] = val[k2];
  }
  __syncthreads();
  if (t < 16)
    Cpart[(size_t)blockIdx.x*16 + t] = lds[0][t]+lds[1][t]+lds[2][t]+lds[3][t];
}

__global__ void k_cfin(const float* __restrict__ Cpart, int nblocks, int n, float* __restrict__ cvec){
  __shared__ float part[256];
  int t = threadIdx.x;
  int slot = t & 15, seg = t >> 4;
  float a = 0.f;
  for (int b=seg; b<nblocks; b+=16) a += Cpart[(size_t)b*16 + slot];
  part[t] = a; __syncthreads();
  if (t < 16){
    float s2 = 0.f;
    for (int i=0;i<16;i++) s2 += part[i*16 + t];
    part[t] = s2/(float)n;           // C[l*4+k], column-exclusive rw
  }
  __syncthreads();
  if (t==0){
    float c[4]; float s2=0.f;
    for (int k2=0;k2<4;k2++){ c[k2] = 0.5f*(part[12+k2] + part[k2*4+3]); s2 += c[k2]; }
    for (int k2=0;k2<4;k2++) cvec[k2] = c[k2]/s2;
  }
}

__global__ void k_ts1(const float* __restrict__ A0,const float* __restrict__ A1,const float* __restrict__ A2,
                      const float* __restrict__ A3, const float* __restrict__ cvec, float* __restrict__ out, int nc){
  int i = blockIdx.x*blockDim.x + threadIdx.x;
  if (i >= nc) return;
  out[i] = cvec[0]*A0[i] + cvec[1]*A1[i] + cvec[2]*A2[i] + cvec[3]*A3[i];
}

__global__ void k_react(const float* __restrict__ ts1, const float* __restrict__ ga, const float* __restrict__ gb,
                        const float* __restrict__ bnp, float* __restrict__ out, int nc){
  int i = blockIdx.x*blockDim.x + threadIdx.x;
  if (i >= nc) return;
  int c = i & 127;
  float t1 = ts1[i];
  float x = t1 + HCONST*(ga[i] + t1*gb[i]);
  out[i] = fmaxf((x-bnp[256+c])*rsqrtf(bnp[384+c]+BN_EPS)*bnp[c]+bnp[128+c], 0.f);
}

// ============================ CG solve ============================
__global__ __launch_bounds__(256) void k_matvec(
  const float* __restrict__ Y, float* __restrict__ out,
  const int* __restrict__ rowptr, const int* __restrict__ colidx,
  const float* __restrict__ dinv, const float* __restrict__ kappa_j,
  const int* __restrict__ done, int n)
{
  if (done && *done) return;
  const int node = blockIdx.x*2 + (threadIdx.x>>7);
  const int c = threadIdx.x & 127;
  if (node >= n) return;
  const float di = dinv[node];
  const float y = Y[(size_t)node*128 + c];
  float acc = -di*di*y;                       // self-loop
  const int s = rowptr[node], e = rowptr[node+1];
  for (int p=s; p<e; p++){
    int j = colidx[p];
    acc += (-di*dinv[j]) * Y[(size_t)j*128 + c];
  }
  float lapv = y + acc;
  float kd = fminf(fmaxf(kappa_j[c],0.f),1.f);
  out[(size_t)node*128 + c] = y + HCONST*kd*lapv;
}

// R = X - matvec(X) = -H*kd*lap(X) ; P = R
__global__ __launch_bounds__(256) void k_mvres(
  const float* __restrict__ X, float* __restrict__ R, float* __restrict__ P,
  const int* __restrict__ rowptr, const int* __restrict__ colidx,
  const float* __restrict__ dinv, const float* __restrict__ kappa_j, int n)
{
  const int node = blockIdx.x*2 + (threadIdx.x>>7);
  const int c = threadIdx.x & 127;
  if (node >= n) return;
  const float di = dinv[node];
  const float y = X[(size_t)node*128 + c];
  float acc = -di*di*y;
  const int s = rowptr[node], e = rowptr[node+1];
  for (int p=s; p<e; p++){
    int j = colidx[p];
    acc += (-di*dinv[j]) * X[(size_t)j*128 + c];
  }
  float lapv = y + acc;
  float kd = fminf(fmaxf(kappa_j[c],0.f),1.f);
  float r = -HCONST*kd*lapv;
  R[(size_t)node*128 + c] = r;
  P[(size_t)node*128 + c] = r;
}

__device__ __forceinline__ float block_reduce(float v){
  __shared__ float sm[256];
  sm[threadIdx.x] = v; __syncthreads();
  for (int o=128;o>0;o>>=1){ if (threadIdx.x<o) sm[threadIdx.x]+=sm[threadIdx.x+o]; __syncthreads(); }
  float r = sm[0]; __syncthreads();
  return r;
}

__device__ __forceinline__ float final_sum(const float* p){
  float a = 0.f;
  for (int i=threadIdx.x; i<RED_BLOCKS; i+=256) a += p[i];
  return block_reduce(a);
}

__global__ __launch_bounds__(256) void k_rr(const float* __restrict__ R, float* __restrict__ part, int nc){
  float acc = 0.f;
  for (int i=blockIdx.x*256+threadIdx.x; i<nc; i+=256*RED_BLOCKS){
    float r = R[i]; acc += r*r;
  }
  float s = block_reduce(acc);
  if (threadIdx.x==0) part[blockIdx.x] = s;
}

__global__ void k_cg_fin0(const float* __restrict__ p, float* __restrict__ scal, int* __restrict__ done, float invNC){
  float s = final_sum(p)*invNC;
  if (threadIdx.x==0){ scal[2]=s; *done=0; }
}

__global__ __launch_bounds__(256) void k_cg_rrpl(const int* __restrict__ done, const float* __restrict__ R,
    const float* __restrict__ P, const float* __restrict__ LP,
    float* __restrict__ pa, float* __restrict__ pb, int nc){
  if (*done) return;
  float a1=0.f, a2=0.f;
  for (int i=blockIdx.x*256+threadIdx.x; i<nc; i+=256*RED_BLOCKS){
    float r=R[i], pv=P[i];
    a1 += r*r; a2 += pv*LP[i];
  }
  float s1 = block_reduce(a1);
  float s2 = block_reduce(a2);
  if (threadIdx.x==0){ pa[blockIdx.x]=s1; pb[blockIdx.x]=s2; }
}

__global__ void k_cg_alpha(const int* __restrict__ done, const float* __restrict__ pa, const float* __restrict__ pb,
                           float* __restrict__ scal, float invNC){
  if (*done) return;
  float rr = final_sum(pa)*invNC;
  float pl = final_sum(pb)*invNC;
  if (threadIdx.x==0) scal[0] = rr/(pl+1e-6f);
}

__global__ __launch_bounds__(256) void k_cg_update(const int* __restrict__ done, const float* __restrict__ scal,
    const float* __restrict__ P, const float* __restrict__ LP, float* __restrict__ X, float* __restrict__ R,
    float* __restrict__ part, int nc){
  if (*done) return;
  float a = scal[0];
  float acc = 0.f;
  for (int i=blockIdx.x*256+threadIdx.x; i<nc; i+=256*RED_BLOCKS){
    X[i] += a*P[i];
    float rn = R[i] - a*LP[i];
    R[i] = rn; acc += rn*rn;
  }
  float s = block_reduce(acc);
  if (threadIdx.x==0) part[blockIdx.x] = s;
}

__global__ void k_cg_step2(int* __restrict__ done, const float* __restrict__ p, float* __restrict__ scal, float invNC){
  if (*done) return;
  float nr = final_sum(p)*invNC;
  if (threadIdx.x==0){
    scal[1] = nr/(scal[2]+1e-6f);    // beta uses OLD nro
    if (nr < 1e-5f) *done = 1; else scal[2] = nr;
  }
}

__global__ void k_cg_pupd(const int* __restrict__ done, const float* __restrict__ scal,
                          const float* __restrict__ R, float* __restrict__ P, int nc){
  if (*done) return;
  int i = blockIdx.x*blockDim.x + threadIdx.x;
  if (i < nc) P[i] = R[i] + scal[1]*P[i];
}

// ============================ output ============================
__global__ __launch_bounds__(256) void k_out(const float* __restrict__ X, const float* __restrict__ Wc,
                                             const float* __restrict__ bc, float* __restrict__ out, int n){
  __shared__ float W[12*128];
  __shared__ float B[12];
  for (int i=threadIdx.x; i<12*128; i+=256) W[i]=Wc[i];
  if (threadIdx.x<12) B[threadIdx.x]=bc[threadIdx.x];
  __syncthreads();
  const int lane = threadIdx.x & 63, wv = threadIdx.x >> 6;
  const int node = blockIdx.x*4 + wv;
  if (node >= n) return;
  float x0 = X[(size_t)node*128 + lane], x1 = X[(size_t)node*128 + 64 + lane];
  float o[12];
  #pragma unroll
  for (int j=0;j<12;j++) o[j] = x0*W[j*128+lane] + x1*W[j*128+64+lane];
  #pragma unroll
  for (int off=1; off<64; off<<=1)
    #pragma unroll
    for (int j=0;j<12;j++) o[j] += __shfl_xor(o[j], off);
  if (lane==0){
    float v[12]; float mx = -1e30f;
    #pragma unroll
    for (int j=0;j<12;j++){ v[j]=o[j]+B[j]; mx = fmaxf(mx, v[j]); }
    float sum = 0.f;
    #pragma unroll
    for (int j=0;j<12;j++) sum += expf(v[j]-mx);
    float lse = logf(sum);
    #pragma unroll
    for (int j=0;j<12;j++) out[(size_t)node*12 + j] = v[j]-mx-lse;
  }
}

// ============================ host ============================
struct GPart { const float* A; int w; const float* W; int ws; const float* b; };

static inline void launch_gemm(int epi, GPart p0, GPart p1, GPart p2, const float* bnp,
                               float* out, int nrows, hipStream_t s,
                               const float* e0=nullptr, const float* e1=nullptr,
                               const float* e2=nullptr, const float* e3=nullptr,
                               const float* uvd=nullptr, float* score=nullptr, int kidx=0){
  dim3 g((nrows+63)/64), b(256);
  #define GARGS p0.A,p0.w,p0.W,p0.ws,p0.b, p1.A,p1.w,p1.W,p1.ws,p1.b, p2.A,p2.w,p2.W,p2.ws,p2.b, bnp,out,nrows, e0,e1,e2,e3, uvd,score,kidx
  if (epi==0)      gemm_kernel<0><<<g,b,0,s>>>(GARGS);
  else if (epi==1) gemm_kernel<1><<<g,b,0,s>>>(GARGS);
  else if (epi==2) gemm_kernel<2><<<g,b,0,s>>>(GARGS);
  else             gemm_kernel<3><<<g,b,0,s>>>(GARGS);
  #undef GARGS
}

extern "C" void kernel_launch(void* const* d_in, const int* in_sizes, int n_in,
                              void* d_out, int out_size, void* d_ws, size_t ws_size,
                              hipStream_t stream)
{
  const float* T    = (const float*)d_in[0];
  const float* TF   = (const float*)d_in[1];
  const int*   EI   = (const int*)  d_in[2];
  const float* Wopen= (const float*)d_in[3];
  const float* bopen= (const float*)d_in[4];
  const float* bnOH = (const float*)d_in[5];
  const float* bnOS = (const float*)d_in[6];
  const float* chw  = (const float*)d_in[7];
  const float* chb  = (const float*)d_in[8];
  const float* tew  = (const float*)d_in[9];
  const float* teb  = (const float*)d_in[10];
  const float* KR1w = (const float*)d_in[11];
  const float* KR1b = (const float*)d_in[12];
  const float* KR2w = (const float*)d_in[13];
  const float* KR2b = (const float*)d_in[14];
  const float* KRU0w= (const float*)d_in[15];
  const float* KRU0b= (const float*)d_in[16];
  const float* kappa= (const float*)d_in[17];
  const float* Hew  = (const float*)d_in[18];
  const float* Heb  = (const float*)d_in[19];
  const float* rsw  = (const float*)d_in[20];
  const float* rsb  = (const float*)d_in[21];
  const float* bnRe = (const float*)d_in[22];
  const float* bnHi = (const float*)d_in[23];
  const float* bnRs = (const float*)d_in[24];
  const float* Wq   = (const float*)d_in[25];
  const float* bq   = (const float*)d_in[26];
  const float* Wk   = (const float*)d_in[27];
  const float* bk   = (const float*)d_in[28];
  const float* mhaf = (const float*)d_in[29];
  const float* Wcl  = (const float*)d_in[30];
  const float* bcl  = (const float*)d_in[31];

  const int n  = in_sizes[0]/12;       // 50000
  const int E  = in_sizes[2]/2;        // 800000
  const int NC = n*128;
  const float invNC = 1.0f/(float)NC;

  // -------- workspace carve (256B aligned regions) --------
  char* base = (char*)d_ws;
  size_t off = 0;
  auto carveF = [&](size_t cnt2)->float*{ float* p=(float*)(base+off); off += ((cnt2*4+255)/256)*256; return p; };
  auto carveI = [&](size_t cnt2)->int*  { int*   p=(int*)  (base+off); off += ((cnt2*4+255)/256)*256; return p; };
  const size_t SLOT = (size_t)NC;
  float* A[4];  for (int l=0;l<4;l++) A[l]=carveF(SLOT);
  float* THs   = carveF(SLOT);
  float* T0s   = carveF(SLOT);
  float* S0    = carveF(SLOT);
  float* S1    = carveF(SLOT);
  float* S2    = carveF(SLOT);
  float* te    = carveF((size_t)n*12);
  float* dinv  = carveF(n);
  float* score = carveF((size_t)n*16);
  float* Mbuf  = carveF(128*128);
  float* uvd   = carveF(272);
  int softBlocks = (n+63)/64;
  float* Cpart = carveF((size_t)softBlocks*16);
  float* part1 = carveF(RED_BLOCKS);
  float* part2a= carveF(RED_BLOCKS);
  float* part2b= carveF(RED_BLOCKS);
  float* scal  = carveF(16);           // [0]=alpha [1]=beta [2]=nro [8..11]=cvec
  int* rowptr  = carveI(n+1);
  int* colidx  = carveI(E);
  int* cnt     = carveI(n);
  int* done    = carveI(4);
  (void)n_in; (void)out_size;
  if (off > ws_size) return;   // insufficient workspace -> clean (diagnosable) failure

  // -------- graph setup --------
  k_zeroi<<<(n+255)/256,256,0,stream>>>(cnt, n);
  k_deg <<<(E+255)/256,256,0,stream>>>(EI, cnt, E);
  k_dinv<<<(n+255)/256,256,0,stream>>>(cnt, dinv, n);
  k_scan<<<1,1024,0,stream>>>(cnt, rowptr, n);
  k_zeroi<<<(n+255)/256,256,0,stream>>>(cnt, n);
  k_fill<<<(E+255)/256,256,0,stream>>>(EI, E, rowptr, cnt, colidx);
  k_mprep<<<64,256,0,stream>>>(Wq, bq, Wk, bk, Mbuf, uvd);

  // -------- open / emb / te --------
  GPart Z = {nullptr,0,nullptr,0,nullptr};
  launch_gemm(0, {T,12,Wopen,12,bopen}, Z, Z, bnOH, T0s, n, stream);
  k_emb<<<(NC+255)/256,256,0,stream>>>(T, chw, chb, bnOS, A[0],A[1],A[2],A[3], S2, n);
  k_te <<<((n*12)+255)/256,256,0,stream>>>(TF, tew, teb, te, n);

  // -------- layers --------
  for (int j=0;j<4;j++){
    const float* TSin  = (j==0) ? S2  : A[(j+3)&3];
    const float* THold = (j==0) ? T0s : THs;
    float* Xs = A[j&3];
    const float* acts[4] = { A[j&3], A[(j+1)&3], A[(j+2)&3], A[(j+3)&3] };

    // rescale -> S0
    launch_gemm(0, {te,12, rsw+(size_t)j*17920, 140, rsb+j*128},
                   {TSin,128, rsw+(size_t)j*17920+12, 140, nullptr}, Z,
                   bnRs+(size_t)j*512, S0, n, stream);
    // He -> THs (in-place over THold for j>=1: block-row-local, safe)
    launch_gemm(0, {T0s,128, Hew+(size_t)j*49152,     384, Heb+j*128},
                   {THold,128, Hew+(size_t)j*49152+128, 384, nullptr},
                   {S0,128, Hew+(size_t)j*49152+256, 384, nullptr},
                   bnHi+(size_t)j*512, THs, n, stream);
    // QK scores: G = acts[k] @ M^T, fused epilogue accumulates s[l][k]
    for (int kk=0;kk<4;kk++)
      launch_gemm(3, {acts[kk],128, Mbuf, 128, nullptr}, Z, Z, nullptr, nullptr, n, stream,
                  acts[0],acts[1],acts[2],acts[3], uvd, score, kk);
    k_soft<<<softBlocks,256,0,stream>>>(score, mhaf, Cpart, n);
    k_cfin<<<1,256,0,stream>>>(Cpart, softBlocks, n, scal+8);
    k_ts1 <<<(NC+255)/256,256,0,stream>>>(acts[0],acts[1],acts[2],acts[3], scal+8, S0, NC);
    // ga -> S1 ; gb -> S2
    launch_gemm(1, {THs,128, KR1w +(size_t)j*16384, 128, KR1b +j*128},
                   {T0s,128, KRU0w+(size_t)j*16384, 128, KRU0b+j*128}, Z,
                   nullptr, S1, n, stream);
    launch_gemm(2, {THs,128, KR2w+(size_t)j*16384, 128, KR2b+j*128}, Z, Z, nullptr, S2, n, stream);
    k_react<<<(NC+255)/256,256,0,stream>>>(S0, S1, S2, bnRe+(size_t)j*512, Xs, NC);

    // CG: X=Xs, R=S0, P=S1, LP=S2
    k_mvres<<<(n+1)/2,256,0,stream>>>(Xs, S0, S1, rowptr, colidx, dinv, kappa+j*128, n);
    k_rr<<<RED_BLOCKS,256,0,stream>>>(S0, part1, NC);
    k_cg_fin0<<<1,256,0,stream>>>(part1, scal, done, invNC);
    for (int it=0; it<5; it++){
      k_matvec  <<<(n+1)/2,256,0,stream>>>(S1, S2, rowptr, colidx, dinv, kappa+j*128, done, n);
      k_cg_rrpl <<<RED_BLOCKS,256,0,stream>>>(done, S0, S1, S2, part2a, part2b, NC);
      k_cg_alpha<<<1,256,0,stream>>>(done, part2a, part2b, scal, invNC);
      k_cg_update<<<RED_BLOCKS,256,0,stream>>>(done, scal, S1, S2, Xs, S0, part1, NC);
      k_cg_step2<<<1,256,0,stream>>>(done, part1, scal, invNC);
      k_cg_pupd <<<(NC+255)/256,256,0,stream>>>(done, scal, S0, S1, NC);
    }
  }

  k_out<<<(n+3)/4,256,0,stream>>>(A[3], Wcl, bcl, (float*)d_out, n);
}

// Round 3
// 3079.325 us; speedup vs baseline: 1.4990x; 1.4990x over previous
//
#include <hip/hip_runtime.h>
#include <math.h>

#define BN_EPS 1e-5f
#define HCONST 0.1f
#define RED_BLOCKS 1024

typedef __attribute__((ext_vector_type(8))) short bh8;     // 8 bf16 (4 VGPR)
typedef __attribute__((ext_vector_type(4))) float f32x4;   // MFMA acc

__device__ __forceinline__ unsigned short f2bf(float x){   // RNE f32->bf16
  unsigned int u = __float_as_uint(x);
  u += 0x7fffu + ((u>>16)&1u);
  return (unsigned short)(u>>16);
}
__device__ __forceinline__ float bf2f(unsigned short h){
  return __uint_as_float(((unsigned int)h)<<16);
}

// ============================ utility ============================
__global__ void k_zeroi(int* __restrict__ p, int n){
  int i = blockIdx.x*blockDim.x + threadIdx.x;
  if (i < n) p[i] = 0;
}

// ============================ setup kernels ============================
__global__ void k_deg(const int* __restrict__ ei, int* __restrict__ cnt, int E){
  int e = blockIdx.x*blockDim.x + threadIdx.x;
  if (e < E) atomicAdd(&cnt[ei[e]], 1);
}

__global__ void k_dinv(const int* __restrict__ cnt, float* __restrict__ dinv, int n){
  int i = blockIdx.x*blockDim.x + threadIdx.x;
  if (i < n) dinv[i] = 1.0f/sqrtf((float)(cnt[i]+1));   // deg includes self-loop
}

__global__ __launch_bounds__(1024) void k_scan(const int* __restrict__ cnt, int* __restrict__ rowptr, int n){
  __shared__ int buf[1024];
  __shared__ int carry;
  int t = threadIdx.x;
  if (t==0) carry = 0;
  __syncthreads();
  for (int base=0; base<n; base+=1024){
    int v = (base+t<n) ? cnt[base+t] : 0;
    buf[t]=v; __syncthreads();
    for (int off=1; off<1024; off<<=1){
      int x = (t>=off) ? buf[t-off] : 0;
      __syncthreads();
      buf[t] += x;
      __syncthreads();
    }
    if (base+t<n) rowptr[base+t] = carry + buf[t] - v;   // exclusive
    __syncthreads();
    if (t==1023) carry += buf[1023];
    __syncthreads();
  }
  if (t==0) rowptr[n] = carry;
}

__global__ void k_fill(const int* __restrict__ ei, int E, const int* __restrict__ rowptr,
                       int* __restrict__ cnt, int* __restrict__ colidx){
  int e = blockIdx.x*blockDim.x + threadIdx.x;
  if (e < E){
    int s = ei[e];
    int pos = atomicAdd(&cnt[s],1);
    colidx[rowptr[s]+pos] = ei[E+e];
  }
}

// M = Wq^T Wk (bf16) ; uvd = [u | v | d0] f32: u = Wk^T bq, v = Wq^T bk, d0 = bq.bk
__global__ __launch_bounds__(256) void k_mprep(const float* __restrict__ Wq, const float* __restrict__ bq,
                                               const float* __restrict__ Wk, const float* __restrict__ bk,
                                               unsigned short* __restrict__ Mb, float* __restrict__ uvd){
  __shared__ float wqc[2][128];
  int t = threadIdx.x;
  int r = t>>7, e = t&127;
  int c0 = blockIdx.x*2;
  wqc[r][e] = Wq[(size_t)e*128 + (c0+r)];   // Wq[i][c], i=e
  __syncthreads();
  float acc = 0.f;
  for (int i=0;i<128;i++) acc += wqc[r][i]*Wk[(size_t)i*128 + e];
  Mb[(size_t)(c0+r)*128 + e] = f2bf(acc);
  if (blockIdx.x==0){
    if (t<128){
      float au=0.f, av=0.f;
      for (int i=0;i<128;i++){ au += bq[i]*Wk[(size_t)i*128+t]; av += Wq[(size_t)i*128+t]*bk[i]; }
      uvd[t] = au; uvd[128+t] = av;
    }
    if (t==0){
      float d=0.f; for (int i=0;i<128;i++) d += bq[i]*bk[i];
      uvd[256] = d;
    }
  }
}

// emb: acts[l][n][c] = relu(bn(chw[c]*T[n,l]+chb[c])) for l=0..3, and l=11 -> TS
__global__ void k_emb(const float* __restrict__ T, const float* __restrict__ chw, const float* __restrict__ chb,
                      const float* __restrict__ bos, float* __restrict__ A0, float* __restrict__ A1,
                      float* __restrict__ A2, float* __restrict__ A3, float* __restrict__ TS, int n){
  int i = blockIdx.x*blockDim.x + threadIdx.x;
  if (i >= n*128) return;
  int node = i>>7, c = i&127;
  float w = chw[c], cb2 = chb[c];
  float g = bos[c], b2 = bos[128+c], m = bos[256+c], v = bos[384+c];
  float rs = rsqrtf(v+BN_EPS)*g;
  const float* Tr = T + (size_t)node*12;
  float x;
  x = w*Tr[0]+cb2;  A0[i] = fmaxf((x-m)*rs+b2, 0.f);
  x = w*Tr[1]+cb2;  A1[i] = fmaxf((x-m)*rs+b2, 0.f);
  x = w*Tr[2]+cb2;  A2[i] = fmaxf((x-m)*rs+b2, 0.f);
  x = w*Tr[3]+cb2;  A3[i] = fmaxf((x-m)*rs+b2, 0.f);
  x = w*Tr[11]+cb2; TS[i] = fmaxf((x-m)*rs+b2, 0.f);
}

// te[n,l] = silu(sum_c te_w[c]*tf[n,c,l] + te_b)
__global__ void k_te(const float* __restrict__ tf, const float* __restrict__ tew, const float* __restrict__ teb,
                     float* __restrict__ te, int n){
  int idx = blockIdx.x*blockDim.x + threadIdx.x;
  if (idx >= n*12) return;
  int node = idx/12, l = idx%12;
  float acc = teb[0];
  const float* p = tf + (size_t)node*240 + l;
  #pragma unroll
  for (int c=0;c<20;c++) acc += tew[c]*p[c*12];
  te[idx] = acc/(1.0f+expf(-acc));
}

// ============================ MFMA GEMM ============================
// out[n, 0..127] = EPI( concat(A parts) @ concat(W parts)^T + biases )
// split-bf16 A (hi+lo), bf16 W (hi only). Tile 64 rows x 128 cols, 2 waves.
// EPI: 0 = bn+relu, 1 = none, 2 = clip(-1,1)
template<int EPI>
__global__ __launch_bounds__(128) void gemm_mfma(
  const float* __restrict__ A0p, int w0, const float* __restrict__ W0p, int ws0, const float* __restrict__ b0p,
  const float* __restrict__ A1p, int w1, const float* __restrict__ W1p, int ws1, const float* __restrict__ b1p,
  const float* __restrict__ A2p, int w2, const float* __restrict__ W2p, int ws2, const float* __restrict__ b2p,
  const float* __restrict__ bnp, float* __restrict__ outp, int nrows)
{
  // pad rows to 40 shorts (80B): bank advance 20 mod 32 -> 2-way (free)
  __shared__ __align__(16) unsigned short Ah[64*40];
  __shared__ __align__(16) unsigned short Al[64*40];
  __shared__ __align__(16) unsigned short Wh[128*40];
  const int t = threadIdx.x;
  const int lane = t & 63;
  const int wv   = t >> 6;           // 2 waves
  const int wcol = wv*64;
  const int K = w0 + w1 + w2;
  const int n0 = blockIdx.x*64;
  f32x4 acc[4][4];
  #pragma unroll
  for (int rt=0;rt<4;rt++)
    #pragma unroll
    for (int ct=0;ct<4;ct++) acc[rt][ct] = (f32x4){0.f,0.f,0.f,0.f};

  for (int k0=0; k0<K; k0+=32){
    { // stage A: 64 rows x 32 k -> split bf16. thread: row=t>>1, 16 k's
      const int row = t>>1, kb = (t&1)*16;
      const int gr = n0 + row;
      #pragma unroll
      for (int g=0; g<4; g++){
        const int k = k0 + kb + g*4;
        float4 v = make_float4(0.f,0.f,0.f,0.f);
        if (gr < nrows && k < K){
          if (k < w0)            v = *(const float4*)&A0p[(size_t)gr*w0 + k];
          else if (k < w0+w1)    v = *(const float4*)&A1p[(size_t)gr*w1 + (k-w0)];
          else                   v = *(const float4*)&A2p[(size_t)gr*w2 + (k-w0-w1)];
        }
        ushort4 hv, lv;
        hv.x=f2bf(v.x); lv.x=f2bf(v.x-bf2f(hv.x));
        hv.y=f2bf(v.y); lv.y=f2bf(v.y-bf2f(hv.y));
        hv.z=f2bf(v.z); lv.z=f2bf(v.z-bf2f(hv.z));
        hv.w=f2bf(v.w); lv.w=f2bf(v.w-bf2f(hv.w));
        const int idx = row*40 + kb + g*4;
        *(ushort4*)&Ah[idx] = hv;
        *(ushort4*)&Al[idx] = lv;
      }
    }
    { // stage W: 128 cols x 32 k -> bf16 hi. thread: c=t, 32 k's
      const int c = t;
      #pragma unroll
      for (int g=0; g<8; g++){
        const int k = k0 + g*4;
        float4 v = make_float4(0.f,0.f,0.f,0.f);
        if (k < K){
          if (k < w0)            v = *(const float4*)&W0p[(size_t)c*ws0 + k];
          else if (k < w0+w1)    v = *(const float4*)&W1p[(size_t)c*ws1 + (k-w0)];
          else                   v = *(const float4*)&W2p[(size_t)c*ws2 + (k-w0-w1)];
        }
        ushort4 hv;
        hv.x=f2bf(v.x); hv.y=f2bf(v.y); hv.z=f2bf(v.z); hv.w=f2bf(v.w);
        *(ushort4*)&Wh[c*40 + g*4] = hv;
      }
    }
    __syncthreads();
    bh8 bfr[4];
    #pragma unroll
    for (int ct=0;ct<4;ct++)
      bfr[ct] = *(const bh8*)&Wh[(wcol + ct*16 + (lane&15))*40 + (lane>>4)*8];
    #pragma unroll
    for (int rt=0;rt<4;rt++){
      const int ar = (rt*16 + (lane&15))*40 + (lane>>4)*8;
      bh8 ah = *(const bh8*)&Ah[ar];
      bh8 al = *(const bh8*)&Al[ar];
      #pragma unroll
      for (int ct=0;ct<4;ct++){
        acc[rt][ct] = __builtin_amdgcn_mfma_f32_16x16x32_bf16(ah, bfr[ct], acc[rt][ct], 0,0,0);
        acc[rt][ct] = __builtin_amdgcn_mfma_f32_16x16x32_bf16(al, bfr[ct], acc[rt][ct], 0,0,0);
      }
    }
    __syncthreads();
  }

  // epilogue. D layout: col=lane&15, row=(lane>>4)*4+reg
  #pragma unroll
  for (int ct=0;ct<4;ct++){
    const int c = wcol + ct*16 + (lane&15);
    float bias = 0.f;
    if (b0p) bias += b0p[c];
    if (b1p) bias += b1p[c];
    if (b2p) bias += b2p[c];
    float rs=0.f, mm=0.f, bb=0.f;
    if constexpr (EPI==0){
      mm = bnp[256+c]; bb = bnp[128+c];
      rs = rsqrtf(bnp[384+c]+BN_EPS)*bnp[c];
    }
    #pragma unroll
    for (int rt=0;rt<4;rt++){
      #pragma unroll
      for (int reg=0;reg<4;reg++){
        const int gr = n0 + rt*16 + (lane>>4)*4 + reg;
        if (gr < nrows){
          float x = acc[rt][ct][reg] + bias;
          if constexpr (EPI==0) x = fmaxf((x-mm)*rs + bb, 0.f);
          if constexpr (EPI==2) x = fminf(fmaxf(x,-1.f),1.f);
          outp[(size_t)gr*128 + c] = x;
        }
      }
    }
  }
}

// ============================ fused QK score stats ============================
// score[node][l*4+k] = a_l.(M a_k + v) + u.a_k + d0   (32 nodes per block)
__global__ __launch_bounds__(256) void k_qkstat(
  const float* __restrict__ a0, const float* __restrict__ a1,
  const float* __restrict__ a2, const float* __restrict__ a3,
  const unsigned short* __restrict__ Mbf, const float* __restrict__ uvdg,
  float* __restrict__ score, int n)
{
  __shared__ __align__(16) unsigned short alds[4*32*136];  // bf16 acts, pad 136
  __shared__ __align__(16) float G[32*132];                // G_k + v
  __shared__ float uv[272];
  __shared__ float psum[256];
  __shared__ float udotp[64];
  const int t = threadIdx.x, lane = t&63, wv = t>>6;
  const int n0 = blockIdx.x*32;
  const float* aptr[4] = {a0,a1,a2,a3};

  for (int i=t; i<257; i+=256) uv[i] = uvdg[i];
  { // stage acts -> bf16: thread: row=t>>3, cb=(t&7)*16 (4 float4 per l)
    const int row = t>>3, cb = (t&7)*16;
    const int gr = n0 + row;
    #pragma unroll
    for (int l=0;l<4;l++){
      #pragma unroll
      for (int g=0;g<4;g++){
        float4 v = make_float4(0.f,0.f,0.f,0.f);
        if (gr < n) v = *(const float4*)&aptr[l][(size_t)gr*128 + cb + g*4];
        ushort4 hv;
        hv.x=f2bf(v.x); hv.y=f2bf(v.y); hv.z=f2bf(v.z); hv.w=f2bf(v.w);
        *(ushort4*)&alds[(l*32+row)*136 + cb + g*4] = hv;
      }
    }
  }
  __syncthreads();

  float vv[2];
  #pragma unroll
  for (int ct=0;ct<2;ct++) vv[ct] = uv[128 + wv*32 + ct*16 + (lane&15)];
  const float d0 = uv[256];

  for (int kq=0; kq<4; kq++){
    // G_k = a_k @ M^T : wave covers cols wv*32..+31, rows 0..31
    f32x4 acc[2][2];
    #pragma unroll
    for (int rt=0;rt<2;rt++)
      #pragma unroll
      for (int ct=0;ct<2;ct++) acc[rt][ct] = (f32x4){0.f,0.f,0.f,0.f};
    #pragma unroll
    for (int ks=0; ks<4; ks++){
      bh8 b[2];
      #pragma unroll
      for (int ct=0;ct<2;ct++)
        b[ct] = *(const bh8*)&Mbf[(size_t)(wv*32 + ct*16 + (lane&15))*128 + ks*32 + (lane>>4)*8];
      #pragma unroll
      for (int rt=0;rt<2;rt++){
        bh8 a = *(const bh8*)&alds[(kq*32 + rt*16 + (lane&15))*136 + ks*32 + (lane>>4)*8];
        #pragma unroll
        for (int ct=0;ct<2;ct++)
          acc[rt][ct] = __builtin_amdgcn_mfma_f32_16x16x32_bf16(a, b[ct], acc[rt][ct], 0,0,0);
      }
    }
    __syncthreads();   // prev dot-phase reads of G/psum complete
    #pragma unroll
    for (int rt=0;rt<2;rt++)
      #pragma unroll
      for (int ct=0;ct<2;ct++)
        #pragma unroll
        for (int reg=0;reg<4;reg++)
          G[(rt*16 + (lane>>4)*4 + reg)*132 + wv*32 + ct*16 + (lane&15)] = acc[rt][ct][reg] + vv[ct];
    __syncthreads();
    { // dot phase: thread = (row=t>>3, half=(t>>2)&1, l=t&3), 64 c's each
      const int l = t&3, hf = (t>>2)&1, row = t>>3;
      const unsigned short* ap  = &alds[(l*32+row)*136 + hf*64];
      const unsigned short* akp = &alds[(kq*32+row)*136 + hf*64];
      const float* gp = &G[row*132 + hf*64];
      float d = 0.f, du = 0.f;
      #pragma unroll 4
      for (int i=0;i<16;i++){
        ushort4 av = *(const ushort4*)&ap[i*4];
        f32x4 gv = *(const f32x4*)&gp[i*4];
        d += bf2f(av.x)*gv[0] + bf2f(av.y)*gv[1] + bf2f(av.z)*gv[2] + bf2f(av.w)*gv[3];
        if (l==0){
          ushort4 akv = *(const ushort4*)&akp[i*4];
          du += uv[hf*64+i*4+0]*bf2f(akv.x) + uv[hf*64+i*4+1]*bf2f(akv.y)
              + uv[hf*64+i*4+2]*bf2f(akv.z) + uv[hf*64+i*4+3]*bf2f(akv.w);
        }
      }
      psum[t] = d;
      if (l==0) udotp[row*2+hf] = du;
      __syncthreads();
      if (hf==0){
        float s = psum[t] + psum[t^4] + udotp[row*2] + udotp[row*2+1] + d0;
        if (n0+row < n) score[(size_t)(n0+row)*16 + l*4 + kq] = s;
      }
      // next-iteration barrier (before G write) protects psum/G reuse
    }
  }
}

// ============================ attention softmax ============================
__global__ __launch_bounds__(256) void k_soft(const float* __restrict__ score, const float* __restrict__ mhaf,
                                              float* __restrict__ Cpart, int n){
  __shared__ float lds[4][16];
  const int t = threadIdx.x;
  const int nl = blockIdx.x*64 + (t>>2);
  const int l  = t&3;
  float val[4];
  if (nl < n){
    float4 s4 = *(const float4*)&score[(size_t)nl*16 + l*4];
    const float SCALE = 0.08838834764831845f;  // 1/sqrt(128)
    float s0=s4.x*SCALE, s1=s4.y*SCALE, s2=s4.z*SCALE, s3=s4.w*SCALE;
    float m = fmaxf(fmaxf(s0,s1),fmaxf(s2,s3));
    float p0=expf(s0-m),p1=expf(s1-m),p2=expf(s2-m),p3=expf(s3-m);
    float rf = fmaxf(mhaf[0],0.f);
    float inv = rf/(p0+p1+p2+p3);
    val[0]=logf(p0*inv+1e-4f); val[1]=logf(p1*inv+1e-4f);
    val[2]=logf(p2*inv+1e-4f); val[3]=logf(p3*inv+1e-4f);
  } else {
    val[0]=val[1]=val[2]=val[3]=0.f;
  }
  #pragma unroll
  for (int off=4; off<64; off<<=1)
    #pragma unroll
    for (int k2=0;k2<4;k2++) val[k2] += __shfl_xor(val[k2], off);
  const int wv = t>>6, lane = t&63;
  if (lane < 4){
    #pragma unroll
    for (int k2=0;k2<4;k2++) lds[wv][lane*4+k2] = val[k2];
  }
  __syncthreads();
  if (t < 16)
    Cpart[(size_t)blockIdx.x*16 + t] = lds[0][t]+lds[1][t]+lds[2][t]+lds[3][t];
}

__global__ void k_cfin(const float* __restrict__ Cpart, int nblocks, int n, float* __restrict__ cvec){
  __shared__ float part[256];
  int t = threadIdx.x;
  int slot = t & 15, seg = t >> 4;
  float a = 0.f;
  for (int b=seg; b<nblocks; b+=16) a += Cpart[(size_t)b*16 + slot];
  part[t] = a; __syncthreads();
  if (t < 16){
    float s2 = 0.f;
    for (int i=0;i<16;i++) s2 += part[i*16 + t];
    part[t] = s2/(float)n;           // C[l*4+k], column-exclusive rw
  }
  __syncthreads();
  if (t==0){
    float c[4]; float s2=0.f;
    for (int k2=0;k2<4;k2++){ c[k2] = 0.5f*(part[12+k2] + part[k2*4+3]); s2 += c[k2]; }
    for (int k2=0;k2<4;k2++) cvec[k2] = c[k2]/s2;
  }
}

__global__ void k_ts1(const float* __restrict__ A0,const float* __restrict__ A1,const float* __restrict__ A2,
                      const float* __restrict__ A3, const float* __restrict__ cvec, float* __restrict__ out, int nc){
  int i = blockIdx.x*blockDim.x + threadIdx.x;
  if (i >= nc) return;
  out[i] = cvec[0]*A0[i] + cvec[1]*A1[i] + cvec[2]*A2[i] + cvec[3]*A3[i];
}

__global__ void k_react(const float* __restrict__ ts1, const float* __restrict__ ga, const float* __restrict__ gb,
                        const float* __restrict__ bnp, float* __restrict__ out, int nc){
  int i = blockIdx.x*blockDim.x + threadIdx.x;
  if (i >= nc) return;
  int c = i & 127;
  float t1 = ts1[i];
  float x = t1 + HCONST*(ga[i] + t1*gb[i]);
  out[i] = fmaxf((x-bnp[256+c])*rsqrtf(bnp[384+c]+BN_EPS)*bnp[c]+bnp[128+c], 0.f);
}

// ============================ CG solve ============================
__global__ __launch_bounds__(256) void k_matvec(
  const float* __restrict__ Y, float* __restrict__ out,
  const int* __restrict__ rowptr, const int* __restrict__ colidx,
  const float* __restrict__ dinv, const float* __restrict__ kappa_j,
  const int* __restrict__ done, int n)
{
  if (done && *done) return;
  const int node = blockIdx.x*2 + (threadIdx.x>>7);
  const int c = threadIdx.x & 127;
  if (node >= n) return;
  const float di = dinv[node];
  const float y = Y[(size_t)node*128 + c];
  float acc = -di*di*y;                       // self-loop
  const int s = rowptr[node], e = rowptr[node+1];
  for (int p=s; p<e; p++){
    int j = colidx[p];
    acc += (-di*dinv[j]) * Y[(size_t)j*128 + c];
  }
  float lapv = y + acc;
  float kd = fminf(fmaxf(kappa_j[c],0.f),1.f);
  out[(size_t)node*128 + c] = y + HCONST*kd*lapv;
}

// R = X - matvec(X) = -H*kd*lap(X) ; P = R
__global__ __launch_bounds__(256) void k_mvres(
  const float* __restrict__ X, float* __restrict__ R, float* __restrict__ P,
  const int* __restrict__ rowptr, const int* __restrict__ colidx,
  const float* __restrict__ dinv, const float* __restrict__ kappa_j, int n)
{
  const int node = blockIdx.x*2 + (threadIdx.x>>7);
  const int c = threadIdx.x & 127;
  if (node >= n) return;
  const float di = dinv[node];
  const float y = X[(size_t)node*128 + c];
  float acc = -di*di*y;
  const int s = rowptr[node], e = rowptr[node+1];
  for (int p=s; p<e; p++){
    int j = colidx[p];
    acc += (-di*dinv[j]) * X[(size_t)j*128 + c];
  }
  float lapv = y + acc;
  float kd = fminf(fmaxf(kappa_j[c],0.f),1.f);
  float r = -HCONST*kd*lapv;
  R[(size_t)node*128 + c] = r;
  P[(size_t)node*128 + c] = r;
}

__device__ __forceinline__ float block_reduce(float v){
  __shared__ float sm[256];
  sm[threadIdx.x] = v; __syncthreads();
  for (int o=128;o>0;o>>=1){ if (threadIdx.x<o) sm[threadIdx.x]+=sm[threadIdx.x+o]; __syncthreads(); }
  float r = sm[0]; __syncthreads();
  return r;
}

__device__ __forceinline__ float final_sum(const float* p){
  float a = 0.f;
  for (int i=threadIdx.x; i<RED_BLOCKS; i+=256) a += p[i];
  return block_reduce(a);
}

__global__ __launch_bounds__(256) void k_rr(const float* __restrict__ R, float* __restrict__ part, int nc){
  float acc = 0.f;
  for (int i=blockIdx.x*256+threadIdx.x; i<nc; i+=256*RED_BLOCKS){
    float r = R[i]; acc += r*r;
  }
  float s = block_reduce(acc);
  if (threadIdx.x==0) part[blockIdx.x] = s;
}

__global__ void k_cg_fin0(const float* __restrict__ p, float* __restrict__ scal, int* __restrict__ done, float invNC){
  float s = final_sum(p)*invNC;
  if (threadIdx.x==0){ scal[2]=s; *done=0; }
}

__global__ __launch_bounds__(256) void k_cg_rrpl(const int* __restrict__ done, const float* __restrict__ R,
    const float* __restrict__ P, const float* __restrict__ LP,
    float* __restrict__ pa, float* __restrict__ pb, int nc){
  if (*done) return;
  float a1=0.f, a2=0.f;
  for (int i=blockIdx.x*256+threadIdx.x; i<nc; i+=256*RED_BLOCKS){
    float r=R[i], pv=P[i];
    a1 += r*r; a2 += pv*LP[i];
  }
  float s1 = block_reduce(a1);
  float s2 = block_reduce(a2);
  if (threadIdx.x==0){ pa[blockIdx.x]=s1; pb[blockIdx.x]=s2; }
}

__global__ void k_cg_alpha(const int* __restrict__ done, const float* __restrict__ pa, const float* __restrict__ pb,
                           float* __restrict__ scal, float invNC){
  if (*done) return;
  float rr = final_sum(pa)*invNC;
  float pl = final_sum(pb)*invNC;
  if (threadIdx.x==0) scal[0] = rr/(pl+1e-6f);
}

__global__ __launch_bounds__(256) void k_cg_update(const int* __restrict__ done, const float* __restrict__ scal,
    const float* __restrict__ P, const float* __restrict__ LP, float* __restrict__ X, float* __restrict__ R,
    float* __restrict__ part, int nc){
  if (*done) return;
  float a = scal[0];
  float acc = 0.f;
  for (int i=blockIdx.x*256+threadIdx.x; i<nc; i+=256*RED_BLOCKS){
    X[i] += a*P[i];
    float rn = R[i] - a*LP[i];
    R[i] = rn; acc += rn*rn;
  }
  float s = block_reduce(acc);
  if (threadIdx.x==0) part[blockIdx.x] = s;
}

__global__ void k_cg_step2(int* __restrict__ done, const float* __restrict__ p, float* __restrict__ scal, float invNC){
  if (*done) return;
  float nr = final_sum(p)*invNC;
  if (threadIdx.x==0){
    scal[1] = nr/(scal[2]+1e-6f);    // beta uses OLD nro
    if (nr < 1e-5f) *done = 1; else scal[2] = nr;
  }
}

__global__ void k_cg_pupd(const int* __restrict__ done, const float* __restrict__ scal,
                          const float* __restrict__ R, float* __restrict__ P, int nc){
  if (*done) return;
  int i = blockIdx.x*blockDim.x + threadIdx.x;
  if (i < nc) P[i] = R[i] + scal[1]*P[i];
}

// ============================ output ============================
__global__ __launch_bounds__(256) void k_out(const float* __restrict__ X, const float* __restrict__ Wc,
                                             const float* __restrict__ bc, float* __restrict__ out, int n){
  __shared__ float W[12*128];
  __shared__ float B[12];
  for (int i=threadIdx.x; i<12*128; i+=256) W[i]=Wc[i];
  if (threadIdx.x<12) B[threadIdx.x]=bc[threadIdx.x];
  __syncthreads();
  const int lane = threadIdx.x & 63, wv = threadIdx.x >> 6;
  const int node = blockIdx.x*4 + wv;
  if (node >= n) return;
  float x0 = X[(size_t)node*128 + lane], x1 = X[(size_t)node*128 + 64 + lane];
  float o[12];
  #pragma unroll
  for (int j=0;j<12;j++) o[j] = x0*W[j*128+lane] + x1*W[j*128+64+lane];
  #pragma unroll
  for (int off=1; off<64; off<<=1)
    #pragma unroll
    for (int j=0;j<12;j++) o[j] += __shfl_xor(o[j], off);
  if (lane==0){
    float v[12]; float mx = -1e30f;
    #pragma unroll
    for (int j=0;j<12;j++){ v[j]=o[j]+B[j]; mx = fmaxf(mx, v[j]); }
    float sum = 0.f;
    #pragma unroll
    for (int j=0;j<12;j++) sum += expf(v[j]-mx);
    float lse = logf(sum);
    #pragma unroll
    for (int j=0;j<12;j++) out[(size_t)node*12 + j] = v[j]-mx-lse;
  }
}

// ============================ host ============================
struct GPart { const float* A; int w; const float* W; int ws; const float* b; };

static inline void launch_gemm(int epi, GPart p0, GPart p1, GPart p2, const float* bnp,
                               float* out, int nrows, hipStream_t s){
  dim3 g((nrows+63)/64), b(128);
  #define GARGS p0.A,p0.w,p0.W,p0.ws,p0.b, p1.A,p1.w,p1.W,p1.ws,p1.b, p2.A,p2.w,p2.W,p2.ws,p2.b, bnp,out,nrows
  if (epi==0)      gemm_mfma<0><<<g,b,0,s>>>(GARGS);
  else if (epi==1) gemm_mfma<1><<<g,b,0,s>>>(GARGS);
  else             gemm_mfma<2><<<g,b,0,s>>>(GARGS);
  #undef GARGS
}

extern "C" void kernel_launch(void* const* d_in, const int* in_sizes, int n_in,
                              void* d_out, int out_size, void* d_ws, size_t ws_size,
                              hipStream_t stream)
{
  const float* T    = (const float*)d_in[0];
  const float* TF   = (const float*)d_in[1];
  const int*   EI   = (const int*)  d_in[2];
  const float* Wopen= (const float*)d_in[3];
  const float* bopen= (const float*)d_in[4];
  const float* bnOH = (const float*)d_in[5];
  const float* bnOS = (const float*)d_in[6];
  const float* chw  = (const float*)d_in[7];
  const float* chb  = (const float*)d_in[8];
  const float* tew  = (const float*)d_in[9];
  const float* teb  = (const float*)d_in[10];
  const float* KR1w = (const float*)d_in[11];
  const float* KR1b = (const float*)d_in[12];
  const float* KR2w = (const float*)d_in[13];
  const float* KR2b = (const float*)d_in[14];
  const float* KRU0w= (const float*)d_in[15];
  const float* KRU0b= (const float*)d_in[16];
  const float* kappa= (const float*)d_in[17];
  const float* Hew  = (const float*)d_in[18];
  const float* Heb  = (const float*)d_in[19];
  const float* rsw  = (const float*)d_in[20];
  const float* rsb  = (const float*)d_in[21];
  const float* bnRe = (const float*)d_in[22];
  const float* bnHi = (const float*)d_in[23];
  const float* bnRs = (const float*)d_in[24];
  const float* Wq   = (const float*)d_in[25];
  const float* bq   = (const float*)d_in[26];
  const float* Wk   = (const float*)d_in[27];
  const float* bk   = (const float*)d_in[28];
  const float* mhaf = (const float*)d_in[29];
  const float* Wcl  = (const float*)d_in[30];
  const float* bcl  = (const float*)d_in[31];

  const int n  = in_sizes[0]/12;       // 50000
  const int E  = in_sizes[2]/2;        // 800000
  const int NC = n*128;
  const float invNC = 1.0f/(float)NC;

  // -------- workspace carve (256B aligned regions) --------
  char* base = (char*)d_ws;
  size_t off = 0;
  auto carveB = [&](size_t bytes)->void*{ void* p=(void*)(base+off); off += ((bytes+255)/256)*256; return p; };
  auto carveF = [&](size_t cnt2)->float*{ return (float*)carveB(cnt2*4); };
  auto carveI = [&](size_t cnt2)->int*  { return (int*)carveB(cnt2*4); };
  const size_t SLOT = (size_t)NC;
  float* A[4];  for (int l=0;l<4;l++) A[l]=carveF(SLOT);
  float* THs   = carveF(SLOT);
  float* T0s   = carveF(SLOT);
  float* S0    = carveF(SLOT);
  float* S1    = carveF(SLOT);
  float* S2    = carveF(SLOT);
  float* te    = carveF((size_t)n*12);
  float* dinv  = carveF(n);
  float* score = carveF((size_t)n*16);
  unsigned short* Mb = (unsigned short*)carveB(128*128*2);
  float* uvd   = carveF(272);
  int softBlocks = (n+63)/64;
  float* Cpart = carveF((size_t)softBlocks*16);
  float* part1 = carveF(RED_BLOCKS);
  float* part2a= carveF(RED_BLOCKS);
  float* part2b= carveF(RED_BLOCKS);
  float* scal  = carveF(16);           // [0]=alpha [1]=beta [2]=nro [8..11]=cvec
  int* rowptr  = carveI(n+1);
  int* colidx  = carveI(E);
  int* cnt     = carveI(n);
  int* done    = carveI(4);
  (void)n_in; (void)out_size;
  if (off > ws_size) return;   // insufficient workspace -> clean failure

  // -------- graph setup --------
  k_zeroi<<<(n+255)/256,256,0,stream>>>(cnt, n);
  k_deg <<<(E+255)/256,256,0,stream>>>(EI, cnt, E);
  k_dinv<<<(n+255)/256,256,0,stream>>>(cnt, dinv, n);
  k_scan<<<1,1024,0,stream>>>(cnt, rowptr, n);
  k_zeroi<<<(n+255)/256,256,0,stream>>>(cnt, n);
  k_fill<<<(E+255)/256,256,0,stream>>>(EI, E, rowptr, cnt, colidx);
  k_mprep<<<64,256,0,stream>>>(Wq, bq, Wk, bk, Mb, uvd);

  // -------- open / emb / te --------
  GPart Z = {nullptr,0,nullptr,0,nullptr};
  launch_gemm(0, {T,12,Wopen,12,bopen}, Z, Z, bnOH, T0s, n, stream);
  k_emb<<<(NC+255)/256,256,0,stream>>>(T, chw, chb, bnOS, A[0],A[1],A[2],A[3], S2, n);
  k_te <<<((n*12)+255)/256,256,0,stream>>>(TF, tew, teb, te, n);

  // -------- layers --------
  for (int j=0;j<4;j++){
    const float* TSin  = (j==0) ? S2  : A[(j+3)&3];
    const float* THold = (j==0) ? T0s : THs;
    float* Xs = A[j&3];
    const float* acts[4] = { A[j&3], A[(j+1)&3], A[(j+2)&3], A[(j+3)&3] };

    // rescale -> S0
    launch_gemm(0, {te,12, rsw+(size_t)j*17920, 140, rsb+j*128},
                   {TSin,128, rsw+(size_t)j*17920+12, 140, nullptr}, Z,
                   bnRs+(size_t)j*512, S0, n, stream);
    // He -> THs (in-place over THold for j>=1: block-row-local, safe)
    launch_gemm(0, {T0s,128, Hew+(size_t)j*49152,     384, Heb+j*128},
                   {THold,128, Hew+(size_t)j*49152+128, 384, nullptr},
                   {S0,128, Hew+(size_t)j*49152+256, 384, nullptr},
                   bnHi+(size_t)j*512, THs, n, stream);
    // fused QK score stats
    k_qkstat<<<(n+31)/32,256,0,stream>>>(acts[0],acts[1],acts[2],acts[3], Mb, uvd, score, n);
    k_soft<<<softBlocks,256,0,stream>>>(score, mhaf, Cpart, n);
    k_cfin<<<1,256,0,stream>>>(Cpart, softBlocks, n, scal+8);
    k_ts1 <<<(NC+255)/256,256,0,stream>>>(acts[0],acts[1],acts[2],acts[3], scal+8, S0, NC);
    // ga -> S1 ; gb -> S2
    launch_gemm(1, {THs,128, KR1w +(size_t)j*16384, 128, KR1b +j*128},
                   {T0s,128, KRU0w+(size_t)j*16384, 128, KRU0b+j*128}, Z,
                   nullptr, S1, n, stream);
    launch_gemm(2, {THs,128, KR2w+(size_t)j*16384, 128, KR2b+j*128}, Z, Z, nullptr, S2, n, stream);
    k_react<<<(NC+255)/256,256,0,stream>>>(S0, S1, S2, bnRe+(size_t)j*512, Xs, NC);

    // CG: X=Xs, R=S0, P=S1, LP=S2
    k_mvres<<<(n+1)/2,256,0,stream>>>(Xs, S0, S1, rowptr, colidx, dinv, kappa+j*128, n);
    k_rr<<<RED_BLOCKS,256,0,stream>>>(S0, part1, NC);
    k_cg_fin0<<<1,256,0,stream>>>(part1, scal, done, invNC);
    for (int it=0; it<5; it++){
      k_matvec  <<<(n+1)/2,256,0,stream>>>(S1, S2, rowptr, colidx, dinv, kappa+j*128, done, n);
      k_cg_rrpl <<<RED_BLOCKS,256,0,stream>>>(done, S0, S1, S2, part2a, part2b, NC);
      k_cg_alpha<<<1,256,0,stream>>>(done, part2a, part2b, scal, invNC);
      k_cg_update<<<RED_BLOCKS,256,0,stream>>>(done, scal, S1, S2, Xs, S0, part1, NC);
      k_cg_step2<<<1,256,0,stream>>>(done, part1, scal, invNC);
      k_cg_pupd <<<(NC+255)/256,256,0,stream>>>(done, scal, S0, S1, NC);
    }
  }

  k_out<<<(n+3)/4,256,0,stream>>>(A[3], Wcl, bcl, (float*)d_out, n);
}

// Round 4
// 2244.794 us; speedup vs baseline: 2.0563x; 1.3718x over previous
//
#include <hip/hip_runtime.h>
#include <math.h>

#define BN_EPS 1e-5f
#define HCONST 0.1f
#define RED_BLOCKS 1024

typedef __attribute__((ext_vector_type(8))) short bh8;     // 8 bf16 (4 VGPR)
typedef __attribute__((ext_vector_type(4))) float f32x4;   // MFMA acc

__device__ __forceinline__ unsigned short f2bf(float x){   // RNE f32->bf16
  unsigned int u = __float_as_uint(x);
  u += 0x7fffu + ((u>>16)&1u);
  return (unsigned short)(u>>16);
}
__device__ __forceinline__ float bf2f(unsigned short h){
  return __uint_as_float(((unsigned int)h)<<16);
}
__device__ __forceinline__ unsigned packbf(float a, float b){
  return ((unsigned)f2bf(b)<<16) | (unsigned)f2bf(a);
}

// ============================ utility ============================
__global__ void k_zeroi(int* __restrict__ p, int n){
  int i = blockIdx.x*blockDim.x + threadIdx.x;
  if (i < n) p[i] = 0;
}

// ============================ setup kernels ============================
__global__ void k_deg(const int* __restrict__ ei, int* __restrict__ cnt, int E){
  int e = blockIdx.x*blockDim.x + threadIdx.x;
  if (e < E) atomicAdd(&cnt[ei[e]], 1);
}

__global__ void k_dinv(const int* __restrict__ cnt, float* __restrict__ dinv, int n){
  int i = blockIdx.x*blockDim.x + threadIdx.x;
  if (i < n) dinv[i] = 1.0f/sqrtf((float)(cnt[i]+1));   // deg includes self-loop
}

__global__ __launch_bounds__(1024) void k_scan(const int* __restrict__ cnt, int* __restrict__ rowptr, int n){
  __shared__ int buf[1024];
  __shared__ int carry;
  int t = threadIdx.x;
  if (t==0) carry = 0;
  __syncthreads();
  for (int base=0; base<n; base+=1024){
    int v = (base+t<n) ? cnt[base+t] : 0;
    buf[t]=v; __syncthreads();
    for (int off=1; off<1024; off<<=1){
      int x = (t>=off) ? buf[t-off] : 0;
      __syncthreads();
      buf[t] += x;
      __syncthreads();
    }
    if (base+t<n) rowptr[base+t] = carry + buf[t] - v;   // exclusive
    __syncthreads();
    if (t==1023) carry += buf[1023];
    __syncthreads();
  }
  if (t==0) rowptr[n] = carry;
}

__global__ void k_fill(const int* __restrict__ ei, int E, const int* __restrict__ rowptr,
                       int* __restrict__ cnt, int* __restrict__ colidx){
  int e = blockIdx.x*blockDim.x + threadIdx.x;
  if (e < E){
    int s = ei[e];
    int pos = atomicAdd(&cnt[s],1);
    colidx[rowptr[s]+pos] = ei[E+e];
  }
}

// M = Wq^T Wk (bf16) ; uvd = [u | v | d0] f32: u = Wk^T bq, v = Wq^T bk, d0 = bq.bk
__global__ __launch_bounds__(256) void k_mprep(const float* __restrict__ Wq, const float* __restrict__ bq,
                                               const float* __restrict__ Wk, const float* __restrict__ bk,
                                               unsigned short* __restrict__ Mb, float* __restrict__ uvd){
  __shared__ float wqc[2][128];
  int t = threadIdx.x;
  int r = t>>7, e = t&127;
  int c0 = blockIdx.x*2;
  wqc[r][e] = Wq[(size_t)e*128 + (c0+r)];   // Wq[i][c], i=e
  __syncthreads();
  float acc = 0.f;
  for (int i=0;i<128;i++) acc += wqc[r][i]*Wk[(size_t)i*128 + e];
  Mb[(size_t)(c0+r)*128 + e] = f2bf(acc);
  if (blockIdx.x==0){
    if (t<128){
      float au=0.f, av=0.f;
      for (int i=0;i<128;i++){ au += bq[i]*Wk[(size_t)i*128+t]; av += Wq[(size_t)i*128+t]*bk[i]; }
      uvd[t] = au; uvd[128+t] = av;
    }
    if (t==0){
      float d=0.f; for (int i=0;i<128;i++) d += bq[i]*bk[i];
      uvd[256] = d;
    }
  }
}

// emb: acts[l][n][c] = relu(bn(chw[c]*T[n,l]+chb[c])) for l=0..3, and l=11 -> TS
__global__ void k_emb(const float* __restrict__ T, const float* __restrict__ chw, const float* __restrict__ chb,
                      const float* __restrict__ bos, float* __restrict__ A0, float* __restrict__ A1,
                      float* __restrict__ A2, float* __restrict__ A3, float* __restrict__ TS, int n){
  int i = blockIdx.x*blockDim.x + threadIdx.x;
  if (i >= n*128) return;
  int node = i>>7, c = i&127;
  float w = chw[c], cb2 = chb[c];
  float g = bos[c], b2 = bos[128+c], m = bos[256+c], v = bos[384+c];
  float rs = rsqrtf(v+BN_EPS)*g;
  const float* Tr = T + (size_t)node*12;
  float x;
  x = w*Tr[0]+cb2;  A0[i] = fmaxf((x-m)*rs+b2, 0.f);
  x = w*Tr[1]+cb2;  A1[i] = fmaxf((x-m)*rs+b2, 0.f);
  x = w*Tr[2]+cb2;  A2[i] = fmaxf((x-m)*rs+b2, 0.f);
  x = w*Tr[3]+cb2;  A3[i] = fmaxf((x-m)*rs+b2, 0.f);
  x = w*Tr[11]+cb2; TS[i] = fmaxf((x-m)*rs+b2, 0.f);
}

// te[n,l] = silu(sum_c te_w[c]*tf[n,c,l] + te_b)
__global__ void k_te(const float* __restrict__ tf, const float* __restrict__ tew, const float* __restrict__ teb,
                     float* __restrict__ te, int n){
  int idx = blockIdx.x*blockDim.x + threadIdx.x;
  if (idx >= n*12) return;
  int node = idx/12, l = idx%12;
  float acc = teb[0];
  const float* p = tf + (size_t)node*240 + l;
  #pragma unroll
  for (int c=0;c<20;c++) acc += tew[c]*p[c*12];
  te[idx] = acc/(1.0f+expf(-acc));
}

// ============================ MFMA GEMM ============================
// out[n, 0..127] = EPI( concat(A parts) @ concat(W parts)^T + biases )
// split-bf16 A (hi+lo), bf16 W (hi only). Tile 64 rows x 128 cols, 2 waves.
// EPI: 0 = bn+relu, 1 = none, 2 = clip(-1,1)
template<int EPI>
__global__ __launch_bounds__(128) void gemm_mfma(
  const float* __restrict__ A0p, int w0, const float* __restrict__ W0p, int ws0, const float* __restrict__ b0p,
  const float* __restrict__ A1p, int w1, const float* __restrict__ W1p, int ws1, const float* __restrict__ b1p,
  const float* __restrict__ A2p, int w2, const float* __restrict__ W2p, int ws2, const float* __restrict__ b2p,
  const float* __restrict__ bnp, float* __restrict__ outp, int nrows)
{
  // pad rows to 40 shorts (80B): bank advance 20 mod 32 -> 2-way (free)
  __shared__ __align__(16) unsigned short Ah[64*40];
  __shared__ __align__(16) unsigned short Al[64*40];
  __shared__ __align__(16) unsigned short Wh[128*40];
  const int t = threadIdx.x;
  const int lane = t & 63;
  const int wv   = t >> 6;           // 2 waves
  const int wcol = wv*64;
  const int K = w0 + w1 + w2;
  const int n0 = blockIdx.x*64;
  f32x4 acc[4][4];
  #pragma unroll
  for (int rt=0;rt<4;rt++)
    #pragma unroll
    for (int ct=0;ct<4;ct++) acc[rt][ct] = (f32x4){0.f,0.f,0.f,0.f};

  for (int k0=0; k0<K; k0+=32){
    { // stage A: 64 rows x 32 k -> split bf16. thread: row=t>>1, 16 k's
      const int row = t>>1, kb = (t&1)*16;
      const int gr = n0 + row;
      #pragma unroll
      for (int g=0; g<4; g++){
        const int k = k0 + kb + g*4;
        float4 v = make_float4(0.f,0.f,0.f,0.f);
        if (gr < nrows && k < K){
          if (k < w0)            v = *(const float4*)&A0p[(size_t)gr*w0 + k];
          else if (k < w0+w1)    v = *(const float4*)&A1p[(size_t)gr*w1 + (k-w0)];
          else                   v = *(const float4*)&A2p[(size_t)gr*w2 + (k-w0-w1)];
        }
        ushort4 hv, lv;
        hv.x=f2bf(v.x); lv.x=f2bf(v.x-bf2f(hv.x));
        hv.y=f2bf(v.y); lv.y=f2bf(v.y-bf2f(hv.y));
        hv.z=f2bf(v.z); lv.z=f2bf(v.z-bf2f(hv.z));
        hv.w=f2bf(v.w); lv.w=f2bf(v.w-bf2f(hv.w));
        const int idx = row*40 + kb + g*4;
        *(ushort4*)&Ah[idx] = hv;
        *(ushort4*)&Al[idx] = lv;
      }
    }
    { // stage W: 128 cols x 32 k -> bf16 hi. thread: c=t, 32 k's
      const int c = t;
      #pragma unroll
      for (int g=0; g<8; g++){
        const int k = k0 + g*4;
        float4 v = make_float4(0.f,0.f,0.f,0.f);
        if (k < K){
          if (k < w0)            v = *(const float4*)&W0p[(size_t)c*ws0 + k];
          else if (k < w0+w1)    v = *(const float4*)&W1p[(size_t)c*ws1 + (k-w0)];
          else                   v = *(const float4*)&W2p[(size_t)c*ws2 + (k-w0-w1)];
        }
        ushort4 hv;
        hv.x=f2bf(v.x); hv.y=f2bf(v.y); hv.z=f2bf(v.z); hv.w=f2bf(v.w);
        *(ushort4*)&Wh[c*40 + g*4] = hv;
      }
    }
    __syncthreads();
    bh8 bfr[4];
    #pragma unroll
    for (int ct=0;ct<4;ct++)
      bfr[ct] = *(const bh8*)&Wh[(wcol + ct*16 + (lane&15))*40 + (lane>>4)*8];
    #pragma unroll
    for (int rt=0;rt<4;rt++){
      const int ar = (rt*16 + (lane&15))*40 + (lane>>4)*8;
      bh8 ah = *(const bh8*)&Ah[ar];
      bh8 al = *(const bh8*)&Al[ar];
      #pragma unroll
      for (int ct=0;ct<4;ct++){
        acc[rt][ct] = __builtin_amdgcn_mfma_f32_16x16x32_bf16(ah, bfr[ct], acc[rt][ct], 0,0,0);
        acc[rt][ct] = __builtin_amdgcn_mfma_f32_16x16x32_bf16(al, bfr[ct], acc[rt][ct], 0,0,0);
      }
    }
    __syncthreads();
  }

  // epilogue. D layout: col=lane&15, row=(lane>>4)*4+reg
  #pragma unroll
  for (int ct=0;ct<4;ct++){
    const int c = wcol + ct*16 + (lane&15);
    float bias = 0.f;
    if (b0p) bias += b0p[c];
    if (b1p) bias += b1p[c];
    if (b2p) bias += b2p[c];
    float rs=0.f, mm=0.f, bb=0.f;
    if constexpr (EPI==0){
      mm = bnp[256+c]; bb = bnp[128+c];
      rs = rsqrtf(bnp[384+c]+BN_EPS)*bnp[c];
    }
    #pragma unroll
    for (int rt=0;rt<4;rt++){
      #pragma unroll
      for (int reg=0;reg<4;reg++){
        const int gr = n0 + rt*16 + (lane>>4)*4 + reg;
        if (gr < nrows){
          float x = acc[rt][ct][reg] + bias;
          if constexpr (EPI==0) x = fmaxf((x-mm)*rs + bb, 0.f);
          if constexpr (EPI==2) x = fminf(fmaxf(x,-1.f),1.f);
          outp[(size_t)gr*128 + c] = x;
        }
      }
    }
  }
}

// ============================ fused QK score stats ============================
// score[node][l*4+k] = a_l.(M a_k + v) + u.a_k + d0   (32 nodes per block)
__global__ __launch_bounds__(256) void k_qkstat(
  const float* __restrict__ a0, const float* __restrict__ a1,
  const float* __restrict__ a2, const float* __restrict__ a3,
  const unsigned short* __restrict__ Mbf, const float* __restrict__ uvdg,
  float* __restrict__ score, int n)
{
  __shared__ __align__(16) unsigned short alds[4*32*136];  // bf16 acts, pad 136
  __shared__ __align__(16) float G[32*132];                // G_k + v
  __shared__ float uv[272];
  __shared__ float psum[256];
  __shared__ float udotp[64];
  const int t = threadIdx.x, lane = t&63, wv = t>>6;
  const int n0 = blockIdx.x*32;
  const float* aptr[4] = {a0,a1,a2,a3};

  for (int i=t; i<257; i+=256) uv[i] = uvdg[i];
  { // stage acts -> bf16
    const int row = t>>3, cb = (t&7)*16;
    const int gr = n0 + row;
    #pragma unroll
    for (int l=0;l<4;l++){
      #pragma unroll
      for (int g=0;g<4;g++){
        float4 v = make_float4(0.f,0.f,0.f,0.f);
        if (gr < n) v = *(const float4*)&aptr[l][(size_t)gr*128 + cb + g*4];
        ushort4 hv;
        hv.x=f2bf(v.x); hv.y=f2bf(v.y); hv.z=f2bf(v.z); hv.w=f2bf(v.w);
        *(ushort4*)&alds[(l*32+row)*136 + cb + g*4] = hv;
      }
    }
  }
  __syncthreads();

  float vv[2];
  #pragma unroll
  for (int ct=0;ct<2;ct++) vv[ct] = uv[128 + wv*32 + ct*16 + (lane&15)];
  const float d0 = uv[256];

  for (int kq=0; kq<4; kq++){
    f32x4 acc[2][2];
    #pragma unroll
    for (int rt=0;rt<2;rt++)
      #pragma unroll
      for (int ct=0;ct<2;ct++) acc[rt][ct] = (f32x4){0.f,0.f,0.f,0.f};
    #pragma unroll
    for (int ks=0; ks<4; ks++){
      bh8 b[2];
      #pragma unroll
      for (int ct=0;ct<2;ct++)
        b[ct] = *(const bh8*)&Mbf[(size_t)(wv*32 + ct*16 + (lane&15))*128 + ks*32 + (lane>>4)*8];
      #pragma unroll
      for (int rt=0;rt<2;rt++){
        bh8 a = *(const bh8*)&alds[(kq*32 + rt*16 + (lane&15))*136 + ks*32 + (lane>>4)*8];
        #pragma unroll
        for (int ct=0;ct<2;ct++)
          acc[rt][ct] = __builtin_amdgcn_mfma_f32_16x16x32_bf16(a, b[ct], acc[rt][ct], 0,0,0);
      }
    }
    __syncthreads();   // prev dot-phase reads of G/psum complete
    #pragma unroll
    for (int rt=0;rt<2;rt++)
      #pragma unroll
      for (int ct=0;ct<2;ct++)
        #pragma unroll
        for (int reg=0;reg<4;reg++)
          G[(rt*16 + (lane>>4)*4 + reg)*132 + wv*32 + ct*16 + (lane&15)] = acc[rt][ct][reg] + vv[ct];
    __syncthreads();
    { // dot phase
      const int l = t&3, hf = (t>>2)&1, row = t>>3;
      const unsigned short* ap  = &alds[(l*32+row)*136 + hf*64];
      const unsigned short* akp = &alds[(kq*32+row)*136 + hf*64];
      const float* gp = &G[row*132 + hf*64];
      float d = 0.f, du = 0.f;
      #pragma unroll 4
      for (int i=0;i<16;i++){
        ushort4 av = *(const ushort4*)&ap[i*4];
        f32x4 gv = *(const f32x4*)&gp[i*4];
        d += bf2f(av.x)*gv[0] + bf2f(av.y)*gv[1] + bf2f(av.z)*gv[2] + bf2f(av.w)*gv[3];
        if (l==0){
          ushort4 akv = *(const ushort4*)&akp[i*4];
          du += uv[hf*64+i*4+0]*bf2f(akv.x) + uv[hf*64+i*4+1]*bf2f(akv.y)
              + uv[hf*64+i*4+2]*bf2f(akv.z) + uv[hf*64+i*4+3]*bf2f(akv.w);
        }
      }
      psum[t] = d;
      if (l==0) udotp[row*2+hf] = du;
      __syncthreads();
      if (hf==0){
        float s = psum[t] + psum[t^4] + udotp[row*2] + udotp[row*2+1] + d0;
        if (n0+row < n) score[(size_t)(n0+row)*16 + l*4 + kq] = s;
      }
    }
  }
}

// ============================ attention softmax ============================
__global__ __launch_bounds__(256) void k_soft(const float* __restrict__ score, const float* __restrict__ mhaf,
                                              float* __restrict__ Cpart, int n){
  __shared__ float lds[4][16];
  const int t = threadIdx.x;
  const int nl = blockIdx.x*64 + (t>>2);
  const int l  = t&3;
  float val[4];
  if (nl < n){
    float4 s4 = *(const float4*)&score[(size_t)nl*16 + l*4];
    const float SCALE = 0.08838834764831845f;  // 1/sqrt(128)
    float s0=s4.x*SCALE, s1=s4.y*SCALE, s2=s4.z*SCALE, s3=s4.w*SCALE;
    float m = fmaxf(fmaxf(s0,s1),fmaxf(s2,s3));
    float p0=expf(s0-m),p1=expf(s1-m),p2=expf(s2-m),p3=expf(s3-m);
    float rf = fmaxf(mhaf[0],0.f);
    float inv = rf/(p0+p1+p2+p3);
    val[0]=logf(p0*inv+1e-4f); val[1]=logf(p1*inv+1e-4f);
    val[2]=logf(p2*inv+1e-4f); val[3]=logf(p3*inv+1e-4f);
  } else {
    val[0]=val[1]=val[2]=val[3]=0.f;
  }
  #pragma unroll
  for (int off=4; off<64; off<<=1)
    #pragma unroll
    for (int k2=0;k2<4;k2++) val[k2] += __shfl_xor(val[k2], off);
  const int wv = t>>6, lane = t&63;
  if (lane < 4){
    #pragma unroll
    for (int k2=0;k2<4;k2++) lds[wv][lane*4+k2] = val[k2];
  }
  __syncthreads();
  if (t < 16)
    Cpart[(size_t)blockIdx.x*16 + t] = lds[0][t]+lds[1][t]+lds[2][t]+lds[3][t];
}

__global__ void k_cfin(const float* __restrict__ Cpart, int nblocks, int n, float* __restrict__ cvec){
  __shared__ float part[256];
  int t = threadIdx.x;
  int slot = t & 15, seg = t >> 4;
  float a = 0.f;
  for (int b=seg; b<nblocks; b+=16) a += Cpart[(size_t)b*16 + slot];
  part[t] = a; __syncthreads();
  if (t < 16){
    float s2 = 0.f;
    for (int i=0;i<16;i++) s2 += part[i*16 + t];
    part[t] = s2/(float)n;           // C[l*4+k]
  }
  __syncthreads();
  if (t==0){
    float c[4]; float s2=0.f;
    for (int k2=0;k2<4;k2++){ c[k2] = 0.5f*(part[12+k2] + part[k2*4+3]); s2 += c[k2]; }
    for (int k2=0;k2<4;k2++) cvec[k2] = c[k2]/s2;
  }
}

// fused ts1 + react: X = relu(bn(ts1 + H*(ga + ts1*gb))), also bf16 copy
__global__ __launch_bounds__(256) void k_react2(
  const float* __restrict__ A0,const float* __restrict__ A1,const float* __restrict__ A2,
  const float* __restrict__ A3, const float* __restrict__ cvec,
  const float* __restrict__ ga, const float* __restrict__ gb,
  const float* __restrict__ bnp, float* __restrict__ X, unsigned* __restrict__ Xb, int nc)
{
  int i = (blockIdx.x*blockDim.x + threadIdx.x)*2;
  if (i >= nc) return;
  float c0=cvec[0], c1=cvec[1], c2=cvec[2], c3=cvec[3];
  float2 a0 = *(const float2*)&A0[i], a1 = *(const float2*)&A1[i];
  float2 a2 = *(const float2*)&A2[i], a3 = *(const float2*)&A3[i];
  float2 g2 = *(const float2*)&ga[i], b2 = *(const float2*)&gb[i];
  int c = i & 127;
  float o[2];
  float t1x = c0*a0.x + c1*a1.x + c2*a2.x + c3*a3.x;
  float t1y = c0*a0.y + c1*a1.y + c2*a2.y + c3*a3.y;
  float xx = t1x + HCONST*(g2.x + t1x*b2.x);
  float xy = t1y + HCONST*(g2.y + t1y*b2.y);
  o[0] = fmaxf((xx-bnp[256+c  ])*rsqrtf(bnp[384+c  ]+BN_EPS)*bnp[c  ]+bnp[128+c  ], 0.f);
  o[1] = fmaxf((xy-bnp[256+c+1])*rsqrtf(bnp[384+c+1]+BN_EPS)*bnp[c+1]+bnp[128+c+1], 0.f);
  *(float2*)&X[i] = make_float2(o[0],o[1]);
  Xb[i>>1] = packbf(o[0],o[1]);
}

// ============================ CG solve ============================
__device__ __forceinline__ float block_reduce(float v){
  __shared__ float sm[256];
  sm[threadIdx.x] = v; __syncthreads();
  for (int o=128;o>0;o>>=1){ if (threadIdx.x<o) sm[threadIdx.x]+=sm[threadIdx.x+o]; __syncthreads(); }
  float r = sm[0]; __syncthreads();
  return r;
}

// R = P = -H*kd*lap(X) (bf16 gather); partial sum of R.R per block
__global__ __launch_bounds__(256) void k_mvres2(
  const float* __restrict__ X, const unsigned* __restrict__ Xb,
  float* __restrict__ R, float* __restrict__ P, unsigned* __restrict__ Pb,
  float* __restrict__ part,
  const int* __restrict__ rowptr, const int* __restrict__ colidx,
  const float* __restrict__ dinv, const float* __restrict__ kappa_j, int n)
{
  const int wv = threadIdx.x>>6, lane = threadIdx.x&63;
  const int node = blockIdx.x*4 + wv;
  float a1 = 0.f;
  if (node < n){
    const float di = dinv[node];
    float2 y = *(const float2*)&X[(size_t)node*128 + lane*2];
    float acc0 = -di*di*y.x, acc1 = -di*di*y.y;
    const int s = __builtin_amdgcn_readfirstlane(rowptr[node]);
    const int e = __builtin_amdgcn_readfirstlane(rowptr[node+1]);
    for (int p=s; p<e; p++){
      int j = __builtin_amdgcn_readfirstlane(colidx[p]);
      float w = -di*dinv[j];
      unsigned xj = Xb[(size_t)j*64 + lane];
      acc0 += w*bf2f((unsigned short)(xj&0xffffu));
      acc1 += w*bf2f((unsigned short)(xj>>16));
    }
    float2 kd2 = *(const float2*)&kappa_j[lane*2];
    float kd0 = fminf(fmaxf(kd2.x,0.f),1.f), kd1 = fminf(fmaxf(kd2.y,0.f),1.f);
    float r0 = -HCONST*kd0*(y.x+acc0);
    float r1 = -HCONST*kd1*(y.y+acc1);
    *(float2*)&R[(size_t)node*128+lane*2] = make_float2(r0,r1);
    *(float2*)&P[(size_t)node*128+lane*2] = make_float2(r0,r1);
    Pb[(size_t)node*64+lane] = packbf(r0,r1);
    a1 = r0*r0 + r1*r1;
  }
  float ssum = block_reduce(a1);
  if (threadIdx.x==0) part[blockIdx.x] = ssum;
}

// LP = P + H*kd*lap(P) (bf16 gather); partial sum of P.LP per block
__global__ __launch_bounds__(256) void k_matvec2(
  const int* __restrict__ done,
  const float* __restrict__ P, const unsigned* __restrict__ Pb,
  float* __restrict__ LP, float* __restrict__ part,
  const int* __restrict__ rowptr, const int* __restrict__ colidx,
  const float* __restrict__ dinv, const float* __restrict__ kappa_j, int n)
{
  if (*done) return;
  const int wv = threadIdx.x>>6, lane = threadIdx.x&63;
  const int node = blockIdx.x*4 + wv;
  float a2 = 0.f;
  if (node < n){
    const float di = dinv[node];
    float2 y = *(const float2*)&P[(size_t)node*128 + lane*2];
    float acc0 = -di*di*y.x, acc1 = -di*di*y.y;
    const int s = __builtin_amdgcn_readfirstlane(rowptr[node]);
    const int e = __builtin_amdgcn_readfirstlane(rowptr[node+1]);
    for (int p=s; p<e; p++){
      int j = __builtin_amdgcn_readfirstlane(colidx[p]);
      float w = -di*dinv[j];
      unsigned xj = Pb[(size_t)j*64 + lane];
      acc0 += w*bf2f((unsigned short)(xj&0xffffu));
      acc1 += w*bf2f((unsigned short)(xj>>16));
    }
    float2 kd2 = *(const float2*)&kappa_j[lane*2];
    float kd0 = fminf(fmaxf(kd2.x,0.f),1.f), kd1 = fminf(fmaxf(kd2.y,0.f),1.f);
    float lp0 = y.x + HCONST*kd0*(y.x+acc0);
    float lp1 = y.y + HCONST*kd1*(y.y+acc1);
    *(float2*)&LP[(size_t)node*128+lane*2] = make_float2(lp0,lp1);
    a2 = y.x*lp0 + y.y*lp1;
  }
  float ssum = block_reduce(a2);
  if (threadIdx.x==0) part[blockIdx.x] = ssum;
}

__global__ void k_cg_fin0(const float* __restrict__ p, int count, float* __restrict__ scal,
                          int* __restrict__ done, float invNC){
  float a = 0.f;
  for (int i=threadIdx.x; i<count; i+=256) a += p[i];
  float s = block_reduce(a)*invNC;
  if (threadIdx.x==0){ scal[2]=s; *done=0; }
}

// alpha = rr_cur / (mean(P.LP)+1e-6) ; rr_cur tracked in scal[2]
__global__ void k_cg_alpha(const int* __restrict__ done, const float* __restrict__ pa, int count,
                           float* __restrict__ scal, float invNC){
  if (*done) return;
  float a = 0.f;
  for (int i=threadIdx.x; i<count; i+=256) a += pa[i];
  float pl = block_reduce(a)*invNC;
  if (threadIdx.x==0) scal[0] = scal[2]/(pl+1e-6f);
}

__global__ __launch_bounds__(256) void k_cg_update(const int* __restrict__ done, const float* __restrict__ scal,
    const float* __restrict__ P, const float* __restrict__ LP, float* __restrict__ X, float* __restrict__ R,
    float* __restrict__ part, int nc){
  if (*done) return;
  float a = scal[0];
  float acc = 0.f;
  for (int i=blockIdx.x*256+threadIdx.x; i<nc; i+=256*RED_BLOCKS){
    X[i] += a*P[i];
    float rn = R[i] - a*LP[i];
    R[i] = rn; acc += rn*rn;
  }
  float s = block_reduce(acc);
  if (threadIdx.x==0) part[blockIdx.x] = s;
}

__global__ void k_cg_step2(int* __restrict__ done, const float* __restrict__ p, float* __restrict__ scal, float invNC){
  if (*done) return;
  float a = 0.f;
  for (int i=threadIdx.x; i<RED_BLOCKS; i+=256) a += p[i];
  float nr = block_reduce(a)*invNC;
  if (threadIdx.x==0){
    scal[1] = nr/(scal[2]+1e-6f);    // beta uses OLD nro
    if (nr < 1e-5f) *done = 1; else scal[2] = nr;
  }
}

__global__ void k_cg_pupd(const int* __restrict__ done, const float* __restrict__ scal,
                          const float* __restrict__ R, float* __restrict__ P, unsigned* __restrict__ Pb, int nc){
  if (*done) return;
  int i = (blockIdx.x*blockDim.x + threadIdx.x)*2;
  if (i < nc){
    float b = scal[1];
    float2 r = *(const float2*)&R[i];
    float2 p = *(const float2*)&P[i];
    p.x = r.x + b*p.x; p.y = r.y + b*p.y;
    *(float2*)&P[i] = p;
    Pb[i>>1] = packbf(p.x,p.y);
  }
}

// ============================ output ============================
__global__ __launch_bounds__(256) void k_out(const float* __restrict__ X, const float* __restrict__ Wc,
                                             const float* __restrict__ bc, float* __restrict__ out, int n){
  __shared__ float W[12*128];
  __shared__ float B[12];
  for (int i=threadIdx.x; i<12*128; i+=256) W[i]=Wc[i];
  if (threadIdx.x<12) B[threadIdx.x]=bc[threadIdx.x];
  __syncthreads();
  const int lane = threadIdx.x & 63, wv = threadIdx.x >> 6;
  const int node = blockIdx.x*4 + wv;
  if (node >= n) return;
  float x0 = X[(size_t)node*128 + lane], x1 = X[(size_t)node*128 + 64 + lane];
  float o[12];
  #pragma unroll
  for (int j=0;j<12;j++) o[j] = x0*W[j*128+lane] + x1*W[j*128+64+lane];
  #pragma unroll
  for (int off=1; off<64; off<<=1)
    #pragma unroll
    for (int j=0;j<12;j++) o[j] += __shfl_xor(o[j], off);
  if (lane==0){
    float v[12]; float mx = -1e30f;
    #pragma unroll
    for (int j=0;j<12;j++){ v[j]=o[j]+B[j]; mx = fmaxf(mx, v[j]); }
    float sum = 0.f;
    #pragma unroll
    for (int j=0;j<12;j++) sum += expf(v[j]-mx);
    float lse = logf(sum);
    #pragma unroll
    for (int j=0;j<12;j++) out[(size_t)node*12 + j] = v[j]-mx-lse;
  }
}

// ============================ host ============================
struct GPart { const float* A; int w; const float* W; int ws; const float* b; };

static inline void launch_gemm(int epi, GPart p0, GPart p1, GPart p2, const float* bnp,
                               float* out, int nrows, hipStream_t s){
  dim3 g((nrows+63)/64), b(128);
  #define GARGS p0.A,p0.w,p0.W,p0.ws,p0.b, p1.A,p1.w,p1.W,p1.ws,p1.b, p2.A,p2.w,p2.W,p2.ws,p2.b, bnp,out,nrows
  if (epi==0)      gemm_mfma<0><<<g,b,0,s>>>(GARGS);
  else if (epi==1) gemm_mfma<1><<<g,b,0,s>>>(GARGS);
  else             gemm_mfma<2><<<g,b,0,s>>>(GARGS);
  #undef GARGS
}

extern "C" void kernel_launch(void* const* d_in, const int* in_sizes, int n_in,
                              void* d_out, int out_size, void* d_ws, size_t ws_size,
                              hipStream_t stream)
{
  const float* T    = (const float*)d_in[0];
  const float* TF   = (const float*)d_in[1];
  const int*   EI   = (const int*)  d_in[2];
  const float* Wopen= (const float*)d_in[3];
  const float* bopen= (const float*)d_in[4];
  const float* bnOH = (const float*)d_in[5];
  const float* bnOS = (const float*)d_in[6];
  const float* chw  = (const float*)d_in[7];
  const float* chb  = (const float*)d_in[8];
  const float* tew  = (const float*)d_in[9];
  const float* teb  = (const float*)d_in[10];
  const float* KR1w = (const float*)d_in[11];
  const float* KR1b = (const float*)d_in[12];
  const float* KR2w = (const float*)d_in[13];
  const float* KR2b = (const float*)d_in[14];
  const float* KRU0w= (const float*)d_in[15];
  const float* KRU0b= (const float*)d_in[16];
  const float* kappa= (const float*)d_in[17];
  const float* Hew  = (const float*)d_in[18];
  const float* Heb  = (const float*)d_in[19];
  const float* rsw  = (const float*)d_in[20];
  const float* rsb  = (const float*)d_in[21];
  const float* bnRe = (const float*)d_in[22];
  const float* bnHi = (const float*)d_in[23];
  const float* bnRs = (const float*)d_in[24];
  const float* Wq   = (const float*)d_in[25];
  const float* bq   = (const float*)d_in[26];
  const float* Wk   = (const float*)d_in[27];
  const float* bk   = (const float*)d_in[28];
  const float* mhaf = (const float*)d_in[29];
  const float* Wcl  = (const float*)d_in[30];
  const float* bcl  = (const float*)d_in[31];

  const int n  = in_sizes[0]/12;       // 50000
  const int E  = in_sizes[2]/2;        // 800000
  const int NC = n*128;
  const float invNC = 1.0f/(float)NC;

  // -------- workspace carve --------
  char* base = (char*)d_ws;
  size_t off = 0;
  auto carveB = [&](size_t bytes)->void*{ void* p=(void*)(base+off); off += ((bytes+255)/256)*256; return p; };
  auto carveF = [&](size_t cnt2)->float*{ return (float*)carveB(cnt2*4); };
  auto carveI = [&](size_t cnt2)->int*  { return (int*)carveB(cnt2*4); };
  const size_t SLOT = (size_t)NC;
  float* A[4];  for (int l=0;l<4;l++) A[l]=carveF(SLOT);
  float* THs   = carveF(SLOT);
  float* T0s   = carveF(SLOT);
  float* S0    = carveF(SLOT);
  float* S1    = carveF(SLOT);
  float* S2    = carveF(SLOT);
  unsigned* Xb = (unsigned*)carveB((size_t)NC*2);   // bf16 shadow of X
  unsigned* Pb = (unsigned*)carveB((size_t)NC*2);   // bf16 shadow of P
  float* te    = carveF((size_t)n*12);
  float* dinv  = carveF(n);
  float* score = carveF((size_t)n*16);
  unsigned short* Mb = (unsigned short*)carveB(128*128*2);
  float* uvd   = carveF(272);
  int softBlocks = (n+63)/64;
  int mvBlocks  = (n+3)/4;
  float* Cpart = carveF((size_t)softBlocks*16);
  float* mvPart= carveF(mvBlocks);
  float* part1 = carveF(RED_BLOCKS);
  float* scal  = carveF(16);           // [0]=alpha [1]=beta [2]=nro [8..11]=cvec
  int* rowptr  = carveI(n+1);
  int* colidx  = carveI(E);
  int* cnt     = carveI(n);
  int* done    = carveI(4);
  (void)n_in; (void)out_size;
  if (off > ws_size) return;   // insufficient workspace -> clean failure

  // -------- graph setup --------
  k_zeroi<<<(n+255)/256,256,0,stream>>>(cnt, n);
  k_deg <<<(E+255)/256,256,0,stream>>>(EI, cnt, E);
  k_dinv<<<(n+255)/256,256,0,stream>>>(cnt, dinv, n);
  k_scan<<<1,1024,0,stream>>>(cnt, rowptr, n);
  k_zeroi<<<(n+255)/256,256,0,stream>>>(cnt, n);
  k_fill<<<(E+255)/256,256,0,stream>>>(EI, E, rowptr, cnt, colidx);
  k_mprep<<<64,256,0,stream>>>(Wq, bq, Wk, bk, Mb, uvd);

  // -------- open / emb / te --------
  GPart Z = {nullptr,0,nullptr,0,nullptr};
  launch_gemm(0, {T,12,Wopen,12,bopen}, Z, Z, bnOH, T0s, n, stream);
  k_emb<<<(NC+255)/256,256,0,stream>>>(T, chw, chb, bnOS, A[0],A[1],A[2],A[3], S2, n);
  k_te <<<((n*12)+255)/256,256,0,stream>>>(TF, tew, teb, te, n);

  // -------- layers --------
  for (int j=0;j<4;j++){
    const float* TSin  = (j==0) ? S2  : A[(j+3)&3];
    const float* THold = (j==0) ? T0s : THs;
    float* Xs = A[j&3];
    const float* acts[4] = { A[j&3], A[(j+1)&3], A[(j+2)&3], A[(j+3)&3] };

    // rescale -> S0
    launch_gemm(0, {te,12, rsw+(size_t)j*17920, 140, rsb+j*128},
                   {TSin,128, rsw+(size_t)j*17920+12, 140, nullptr}, Z,
                   bnRs+(size_t)j*512, S0, n, stream);
    // He -> THs (in-place over THold for j>=1: block-row-local, safe)
    launch_gemm(0, {T0s,128, Hew+(size_t)j*49152,     384, Heb+j*128},
                   {THold,128, Hew+(size_t)j*49152+128, 384, nullptr},
                   {S0,128, Hew+(size_t)j*49152+256, 384, nullptr},
                   bnHi+(size_t)j*512, THs, n, stream);
    // fused QK score stats + softmax/C
    k_qkstat<<<(n+31)/32,256,0,stream>>>(acts[0],acts[1],acts[2],acts[3], Mb, uvd, score, n);
    k_soft<<<softBlocks,256,0,stream>>>(score, mhaf, Cpart, n);
    k_cfin<<<1,256,0,stream>>>(Cpart, softBlocks, n, scal+8);
    // ga -> S1 ; gb -> S2
    launch_gemm(1, {THs,128, KR1w +(size_t)j*16384, 128, KR1b +j*128},
                   {T0s,128, KRU0w+(size_t)j*16384, 128, KRU0b+j*128}, Z,
                   nullptr, S1, n, stream);
    launch_gemm(2, {THs,128, KR2w+(size_t)j*16384, 128, KR2b+j*128}, Z, Z, nullptr, S2, n, stream);
    // fused ts1+react -> Xs (f32) + Xb (bf16)
    k_react2<<<(NC/2+255)/256,256,0,stream>>>(acts[0],acts[1],acts[2],acts[3], scal+8, S1, S2,
                                              bnRe+(size_t)j*512, Xs, Xb, NC);

    // CG: X=Xs, R=S0, P=S1 (+Pb), LP=S2
    k_mvres2<<<mvBlocks,256,0,stream>>>(Xs, Xb, S0, S1, Pb, mvPart, rowptr, colidx, dinv, kappa+j*128, n);
    k_cg_fin0<<<1,256,0,stream>>>(mvPart, mvBlocks, scal, done, invNC);
    for (int it=0; it<5; it++){
      k_matvec2 <<<mvBlocks,256,0,stream>>>(done, S1, Pb, S2, mvPart, rowptr, colidx, dinv, kappa+j*128, n);
      k_cg_alpha<<<1,256,0,stream>>>(done, mvPart, mvBlocks, scal, invNC);
      k_cg_update<<<RED_BLOCKS,256,0,stream>>>(done, scal, S1, S2, Xs, S0, part1, NC);
      k_cg_step2<<<1,256,0,stream>>>(done, part1, scal, invNC);
      k_cg_pupd <<<(NC/2+255)/256,256,0,stream>>>(done, scal, S0, S1, Pb, NC);
    }
  }

  k_out<<<(n+3)/4,256,0,stream>>>(A[3], Wcl, bcl, (float*)d_out, n);
}